// Round 1
// baseline (757.872 us; speedup 1.0000x reference)
//
#include <hip/hip_runtime.h>

typedef _Float16 f16;
typedef __attribute__((ext_vector_type(8))) _Float16 f16x8;
typedef __attribute__((ext_vector_type(4))) _Float16 f16x4;
typedef __attribute__((ext_vector_type(4))) float f32x4;

// ---- global_load_lds width-16 helper (m97 pattern) ----
typedef const __attribute__((address_space(1))) unsigned int* gas_ptr;
typedef __attribute__((address_space(3))) unsigned int* las_ptr;

__device__ __forceinline__ void gload16(const f16* g, f16* l) {
  __builtin_amdgcn_global_load_lds((gas_ptr)g, (las_ptr)l, 16, 0, 0);
}

// =====================================================================
// Generic MFMA GEMM core: C[m,n] = scale * sum_k A[m,k]*B[n,k] (+bias)
// A: (WM*64 rows) row-major lda, k contiguous; B: (WN*64 rows = out cols)
// row-major ldb, k contiguous. BK=64, 16x16x32 f16 MFMA, fp32 acc.
// kLen must be a multiple of 64. All tile dims divide problem dims.
// =====================================================================
template<int WM, int WN, bool OUT32>
__device__ __forceinline__ void gemm_core(
    const f16* __restrict__ A, int lda,
    const f16* __restrict__ B, int ldb,
    int kLen,
    f16* lsA, f16* lsB,
    float* __restrict__ C32, f16* __restrict__ C16, int ldc,
    float scale, const float* __restrict__ biasC, const float* __restrict__ biasR)
{
  constexpr int T   = WM * WN * 64;      // threads per block
  constexpr int nA  = (WM * 64 * 8) / T; // global_load_lds insts for A tile
  constexpr int nB  = (WN * 64 * 8) / T;
  constexpr int RPI = T / 8;             // rows staged per inst
  const int t    = threadIdx.x;
  const int lane = t & 63;
  const int wave = t >> 6;
  const int wm   = wave / WN;
  const int wn   = wave % WN;

  f32x4 acc[4][4];
  const f32x4 z4 = {0.f, 0.f, 0.f, 0.f};
#pragma unroll
  for (int i = 0; i < 4; ++i)
#pragma unroll
    for (int j = 0; j < 4; ++j) acc[i][j] = z4;

  const int r_ = t >> 3;            // row within staging group
  const int c_ = (t & 7) * 8;       // k offset (f16 units)
  const int ldsOff = (wave << 9);   // wave * 64 lanes * 8 f16

  for (int kt = 0; kt < kLen; kt += 64) {
#pragma unroll
    for (int i = 0; i < nA; ++i) {
      const f16* g = A + (size_t)(i * RPI + r_) * lda + kt + c_;
      gload16(g, lsA + i * (T * 8) + ldsOff);
    }
#pragma unroll
    for (int i = 0; i < nB; ++i) {
      const f16* g = B + (size_t)(i * RPI + r_) * ldb + kt + c_;
      gload16(g, lsB + i * (T * 8) + ldsOff);
    }
    __syncthreads();   // compiler drains vmcnt(0) before s_barrier
#pragma unroll
    for (int ks = 0; ks < 2; ++ks) {
      f16x8 af[4], bf[4];
#pragma unroll
      for (int i = 0; i < 4; ++i)
        af[i] = *(const f16x8*)&lsA[(wm * 64 + i * 16 + (lane & 15)) * 64 + ks * 32 + (lane >> 4) * 8];
#pragma unroll
      for (int j = 0; j < 4; ++j)
        bf[j] = *(const f16x8*)&lsB[(wn * 64 + j * 16 + (lane & 15)) * 64 + ks * 32 + (lane >> 4) * 8];
#pragma unroll
      for (int i = 0; i < 4; ++i)
#pragma unroll
        for (int j = 0; j < 4; ++j)
          acc[i][j] = __builtin_amdgcn_mfma_f32_16x16x32_f16(af[i], bf[j], acc[i][j], 0, 0, 0);
    }
    __syncthreads();
  }

  // epilogue: C/D layout col=lane&15, row=(lane>>4)*4+reg (m89-verified)
  const int lc = lane & 15;
  const int lr = (lane >> 4) * 4;
#pragma unroll
  for (int j = 0; j < 4; ++j) {
    const int col = wn * 64 + j * 16 + lc;
    const float bC = biasC ? biasC[col] : 0.f;
#pragma unroll
    for (int i = 0; i < 4; ++i) {
      const int rbase = wm * 64 + i * 16 + lr;
#pragma unroll
      for (int r = 0; r < 4; ++r) {
        const int row = rbase + r;
        float v = acc[i][j][r] * scale + bC;
        if (biasR) v += biasR[row];
        if (OUT32) C32[(size_t)row * ldc + col] = v;
        else       C16[(size_t)row * ldc + col] = (f16)v;
      }
    }
  }
}

// ---- generic single-GEMM wrapper ----
template<int WM, int WN, bool OUT32>
__global__ __launch_bounds__(WM * WN * 64) void k_gemm(
    const f16* A, int lda, const f16* B, int ldb, int kLen,
    float* C32, f16* C16, int ldc, float scale,
    const float* biasC, const float* biasR)
{
  __shared__ f16 lsA[WM * 64 * 64];
  __shared__ f16 lsB[WN * 64 * 64];
  const size_t rt = blockIdx.y, ct = blockIdx.x;
  gemm_core<WM, WN, OUT32>(
      A + rt * (WM * 64) * (size_t)lda, lda,
      B + ct * (WN * 64) * (size_t)ldb, ldb, kLen,
      lsA, lsB,
      OUT32 ? C32 + rt * (WM * 64) * (size_t)ldc + ct * (WN * 64) : nullptr,
      OUT32 ? nullptr : C16 + rt * (WM * 64) * (size_t)ldc + ct * (WN * 64), ldc,
      scale,
      biasC ? biasC + ct * (WN * 64) : nullptr,
      biasR ? biasR + rt * (WM * 64) : nullptr);
}

// ---- cast x -> f16 in BOTH layouts: Xf (b*4096 x 1024) and XT (b, 1024, 4096) ----
__global__ __launch_bounds__(256) void k_cast_xt(const float* __restrict__ x,
                                                 f16* __restrict__ Xf,
                                                 f16* __restrict__ XT)
{
  __shared__ f16 tile[64][68];   // pad 68: 8B-aligned rows, modest conflicts
  const int b = blockIdx.z, bi = blockIdx.y, bj = blockIdx.x; // bi: n-tile(64), bj: m-tile(16)
  const int r0 = threadIdx.x >> 4;            // 0..15
  const int c4 = (threadIdx.x & 15) * 4;      // 0..60
  const float* xb = x + ((size_t)b * 4096 + (size_t)bi * 64) * 1024 + bj * 64;
#pragma unroll
  for (int rr = 0; rr < 4; ++rr) {
    const int row = rr * 16 + r0;             // n within tile
    const float4 v = *(const float4*)(xb + (size_t)row * 1024 + c4);
    f16x4 h = {(f16)v.x, (f16)v.y, (f16)v.z, (f16)v.w};
    *(f16x4*)&tile[row][c4] = h;
    *(f16x4*)(Xf + ((size_t)b * 4096 + (size_t)bi * 64 + row) * 1024 + bj * 64 + c4) = h;
  }
  __syncthreads();
#pragma unroll
  for (int rr = 0; rr < 4; ++rr) {
    const int col = rr * 16 + r0;             // m within tile
    f16x4 h = {tile[c4 + 0][col], tile[c4 + 1][col], tile[c4 + 2][col], tile[c4 + 3][col]};
    *(f16x4*)(XT + ((size_t)b * 1024 + (size_t)bj * 64 + col) * 4096 + (size_t)bi * 64 + c4) = h;
  }
}

// ---- cast weights -> f16: Wq,Wk,Wv,Wo then E,F (each 1M f32 elems) ----
__global__ __launch_bounds__(256) void k_cast_w(
    const float* w0, const float* w1, const float* w2,
    const float* w3, const float* w4, const float* w5, f16* __restrict__ d)
{
  const size_t i = ((size_t)blockIdx.x * 256 + threadIdx.x) * 4;
  const int seg = (int)(i >> 20);
  const float* s = (seg == 0) ? w0 : (seg == 1) ? w1 : (seg == 2) ? w2
                 : (seg == 3) ? w3 : (seg == 4) ? w4 : w5;
  const float4 v = *(const float4*)(s + (i & 1048575));
  f16x4 o = {(f16)v.x, (f16)v.y, (f16)v.z, (f16)v.w};
  *(f16x4*)(d + i) = o;
}

// ---- row sums of E and F (f32 inputs) for the rank-1 bias terms ----
__global__ __launch_bounds__(256) void k_rowsum(const float* __restrict__ E,
                                                const float* __restrict__ F,
                                                float* __restrict__ rs)
{
  const int r = blockIdx.x * 4 + (threadIdx.x >> 6);   // 0..511
  const int lane = threadIdx.x & 63;
  const float* src = (r < 256) ? (E + (size_t)r * 4096) : (F + (size_t)(r - 256) * 4096);
  float s = 0.f;
#pragma unroll
  for (int i = 0; i < 16; ++i) {
    const float4 v = *(const float4*)(src + i * 256 + lane * 4);
    s += v.x + v.y + v.z + v.w;
  }
#pragma unroll
  for (int o = 32; o; o >>= 1) s += __shfl_xor(s, o);
  if (lane == 0) rs[r] = s;
}

// ---- EX/FX: C[(E|F) r, m] = sum_n EF[r,n] * XT[b,m,n]; split-K=4 ----
// grid (8, 4, 16): x=ct (1024/128), y=rt (512/128), z = s*4 + b
__global__ __launch_bounds__(256) void k_exfx(const f16* __restrict__ EF,
                                              const f16* __restrict__ XT,
                                              float* __restrict__ part)
{
  __shared__ f16 lsA[128 * 64];
  __shared__ f16 lsB[128 * 64];
  const int z = blockIdx.z; const int b = z & 3; const int s = z >> 2;
  const int rt = blockIdx.y, ct = blockIdx.x;
  const f16* A = EF + (size_t)rt * 128 * 4096 + s * 1024;
  const f16* B = XT + (size_t)b * 1024 * 4096 + (size_t)ct * 128 * 4096 + s * 1024;
  float* C = part + (size_t)z * (512 * 1024) + (size_t)rt * 128 * 1024 + ct * 128;
  gemm_core<2, 2, true>(A, 4096, B, 4096, 1024, lsA, lsB, C, nullptr, 1024, 1.f, nullptr, nullptr);
}

// ---- reduce EX/FX split-K partials -> f16 (b, 512, 1024) ----
__global__ __launch_bounds__(256) void k_reduce2(const float* __restrict__ part,
                                                 f16* __restrict__ EXf)
{
  const size_t i = ((size_t)blockIdx.x * 256 + threadIdx.x) * 4;  // < 2M
  const size_t b = i >> 19;
  const size_t idx = i & 524287;
  const float4 a = *(const float4*)(part + (0 * 4 + b) * 524288 + idx);
  const float4 c1 = *(const float4*)(part + (1 * 4 + b) * 524288 + idx);
  const float4 c2 = *(const float4*)(part + (2 * 4 + b) * 524288 + idx);
  const float4 c3 = *(const float4*)(part + (3 * 4 + b) * 524288 + idx);
  f16x4 o = {(f16)(a.x + c1.x + c2.x + c3.x), (f16)(a.y + c1.y + c2.y + c3.y),
             (f16)(a.z + c1.z + c2.z + c3.z), (f16)(a.w + c1.w + c2.w + c3.w)};
  *(f16x4*)(EXf + i) = o;
}

// ---- Kp = EX·Wk^T (rows b*256+r, cols hd) ; Vp^T = Wv·FX^T (rows hd, cols b*256+r)
// split-K=2 (512 each). grid (8, 8, 4): z = s*2 + which
__global__ __launch_bounds__(256) void k_kpvp(const f16* __restrict__ EXf,
                                              const f16* __restrict__ W16,
                                              float* __restrict__ p2)
{
  __shared__ f16 lsA[128 * 64];
  __shared__ f16 lsB[128 * 64];
  const int z = blockIdx.z; const int which = z & 1; const int s = z >> 1;
  const int rt = blockIdx.y, ct = blockIdx.x;
  const f16 *A, *B;
  if (which == 0) {  // Kp
    const int b = rt >> 1, r0 = (rt & 1) * 128;
    A = EXf + ((size_t)b * 512 + r0) * 1024 + s * 512;
    B = W16 + 1048576 + (size_t)ct * 128 * 1024 + s * 512;        // Wk
  } else {           // Vp^T
    const int b = ct >> 1, r0 = (ct & 1) * 128;
    A = W16 + 2 * 1048576 + (size_t)rt * 128 * 1024 + s * 512;    // Wv
    B = EXf + ((size_t)b * 512 + 256 + r0) * 1024 + s * 512;
  }
  float* C = p2 + (size_t)(s * 2 + which) * 1048576 + (size_t)rt * 128 * 1024 + ct * 128;
  gemm_core<2, 2, true>(A, 1024, B, 1024, 512, lsA, lsB, C, nullptr, 1024, 1.f, nullptr, nullptr);
}

// ---- reduce Kp/Vp partials + rank-1 bias -> f16 KpVp region ----
// out: Kp (4,256,1024) then VpT (4,1024,256); adds rowsumE[r]*bk[hd] / bv[hd]*rowsumF[r]
__global__ __launch_bounds__(256) void k_reduce3(const float* __restrict__ p2,
                                                 f16* __restrict__ KpVp,
                                                 const float* __restrict__ rs,
                                                 const float* __restrict__ bk,
                                                 const float* __restrict__ bv)
{
  const size_t i = ((size_t)blockIdx.x * 256 + threadIdx.x) * 4;  // < 2M
  const int half = (int)(i >> 20);
  const size_t j = i & 1048575;
  size_t pidx; float r1[4];
  if (half == 0) {           // Kp: j = (b*256+r)*1024 + hd  (partKp same layout)
    const int r  = (int)((j >> 10) & 255);
    const int hd = (int)(j & 1023);
    pidx = j;
    const float se = rs[r];
#pragma unroll
    for (int t = 0; t < 4; ++t) r1[t] = se * bk[hd + t];
  } else {                   // VpT: j = (b*1024+hd)*256 + r ; part at [hd][b*256+r]
    const int b  = (int)(j >> 18);
    const int hd = (int)((j >> 8) & 1023);
    const int r  = (int)(j & 255);
    pidx = (size_t)hd * 1024 + (size_t)b * 256 + r;
    const float bb = bv[hd];
#pragma unroll
    for (int t = 0; t < 4; ++t) r1[t] = bb * rs[256 + r + t];
  }
  const float4 a = *(const float4*)(p2 + (size_t)(0 * 2 + half) * 1048576 + pidx);
  const float4 c = *(const float4*)(p2 + (size_t)(1 * 2 + half) * 1048576 + pidx);
  f16x4 o = {(f16)(a.x + c.x + r1[0]), (f16)(a.y + c.y + r1[1]),
             (f16)(a.z + c.z + r1[2]), (f16)(a.w + c.w + r1[3])};
  *(f16x4*)(KpVp + i) = o;
}

// ---- stage 3: scores = Q·Kp^T / 8 -> fp32 (d_out attn region) ----
__global__ __launch_bounds__(256) void k_scores(const f16* __restrict__ Q,
                                                const f16* __restrict__ Kp,
                                                float* __restrict__ S)
{
  __shared__ f16 lsA[128 * 64];
  __shared__ f16 lsB[128 * 64];
  const int bh = blockIdx.z; const int b = bh >> 4; const int h = bh & 15;
  const size_t rt = blockIdx.y, ct = blockIdx.x;
  const f16* A = Q + (size_t)b * 4096 * 1024 + h * 64 + rt * 128 * 1024;
  const f16* B = Kp + (size_t)b * 262144 + h * 64 + ct * 128 * 1024;
  float* C = S + (size_t)bh * 4096 * 256 + rt * 128 * 256 + ct * 128;
  gemm_core<2, 2, true>(A, 1024, B, 1024, 64, lsA, lsB, C, nullptr, 256, 0.125f, nullptr, nullptr);
}

// ---- stage 3.5: fp32 softmax over rows of 256, one wave per row (per batch) ----
__global__ __launch_bounds__(256) void k_softmax(const float* __restrict__ S,
                                                 f16* __restrict__ P)
{
  const int row  = blockIdx.x * 4 + (threadIdx.x >> 6);  // local row within batch
  const int lane = threadIdx.x & 63;
  const float4 v = *(const float4*)(S + (size_t)row * 256 + lane * 4);
  float m = fmaxf(fmaxf(v.x, v.y), fmaxf(v.z, v.w));
#pragma unroll
  for (int o = 32; o; o >>= 1) m = fmaxf(m, __shfl_xor(m, o));
  const float e0 = __expf(v.x - m), e1 = __expf(v.y - m);
  const float e2 = __expf(v.z - m), e3 = __expf(v.w - m);
  float sum = e0 + e1 + e2 + e3;
#pragma unroll
  for (int o = 32; o; o >>= 1) sum += __shfl_xor(sum, o);
  const float inv = 1.f / sum;
  f16x4 p = {(f16)(e0 * inv), (f16)(e1 * inv), (f16)(e2 * inv), (f16)(e3 * inv)};
  *(f16x4*)(P + (size_t)row * 256 + lane * 4) = p;
}

// ---- stage 4: out_pre = P·Vp  (tile 128x64, 2 waves; one batch at a time) ----
__global__ __launch_bounds__(128) void k_pv(const f16* __restrict__ P,
                                            const f16* __restrict__ VpT,
                                            f16* __restrict__ OP, int b)
{
  __shared__ f16 lsA[128 * 64];
  __shared__ f16 lsB[64 * 64];
  const int h = blockIdx.z;           // head
  const size_t rt = blockIdx.y;
  const f16* A = P + ((size_t)h * 4096 + rt * 128) * 256;   // P for this batch
  const f16* B = VpT + (size_t)b * 262144 + (size_t)h * 64 * 256;
  f16* C = OP + (size_t)b * 4096 * 1024 + rt * 128 * 1024 + h * 64;
  gemm_core<2, 1, false>(A, 256, B, 256, 256, lsA, lsB, nullptr, C, 1024, 1.f, nullptr, nullptr);
}

// =====================================================================
// Algebraic restructure: Kp = E·(X·Wk^T) = (E·X)·Wk^T (+ rowsum(E)⊗bk).
// Full K/V (16384x1024) are never materialized. FLOPs 172G -> 107.5G.
//
// Workspace layout (144 MiB, regions time-aliased; fits old 151MB budget):
//  R0 @0      (32MiB): Xf16 -> EXf (4MiB, after Q proj) + rowsum @+4MiB -> P16 (one batch)
//  R1 @32MiB  (32MiB): XT16 (b,1024,4096) -> out_pre16
//  R2 @64MiB  (32MiB): Q16
//  R3 @96MiB  (32MiB): EX split-K partials (32MiB) -> KpVp partials (16MiB)
//  tail @128MiB (16MiB): W16 (8MiB: Wq,Wk,Wv,Wo) + EF16 (4MiB) + KpVp (4MiB)
// =====================================================================
extern "C" void kernel_launch(void* const* d_in, const int* in_sizes, int n_in,
                              void* d_out, int out_size, void* d_ws, size_t ws_size,
                              hipStream_t stream) {
  const float* x  = (const float*)d_in[0];
  const float* Wq = (const float*)d_in[1];
  const float* bq = (const float*)d_in[2];
  const float* Wk = (const float*)d_in[3];
  const float* bk = (const float*)d_in[4];
  const float* Wv = (const float*)d_in[5];
  const float* bv = (const float*)d_in[6];
  const float* E  = (const float*)d_in[7];
  const float* F  = (const float*)d_in[8];
  const float* Wo = (const float*)d_in[9];
  const float* bo = (const float*)d_in[10];

  float* out = (float*)d_out;           // 16,777,216 f32
  float* S   = out + 16777216;          // attn_score region, 67,108,864 f32

  char* w = (char*)d_ws;
  f16*   Xf     = (f16*)w;                              // R0
  f16*   EXf    = (f16*)w;                              // R0 (after Xf dead)
  float* rowsum = (float*)(w + 4 * 1048576);            // R0 + 4MiB
  f16*   Pf     = (f16*)w;                              // R0 (after EXf dead)
  f16*   XT     = (f16*)(w + 33554432);                 // R1
  f16*   OPf    = (f16*)(w + 33554432);                 // R1 (after XT dead)
  f16*   Qf     = (f16*)(w + (size_t)2 * 33554432);     // R2
  float* part   = (float*)(w + (size_t)3 * 33554432);   // R3 (EX partials)
  float* part2  = (float*)(w + (size_t)3 * 33554432);   // R3 (KpVp partials)
  f16*   W16    = (f16*)(w + (size_t)4 * 33554432);     // tail
  f16*   EF16   = W16 + (size_t)4 * 1048576;
  f16*   KpVp   = (f16*)(w + (size_t)4 * 33554432 + 12582912);

  // 1. casts: x -> Xf + XT (transposed), weights -> f16
  k_cast_xt<<<dim3(16, 64, 4), 256, 0, stream>>>(x, Xf, XT);
  k_cast_w<<<6144, 256, 0, stream>>>(Wq, Wk, Wv, Wo, E, F, W16);

  // 2. Q projection (Xf last use)
  k_gemm<2, 2, false><<<dim3(8, 128), 256, 0, stream>>>(
      Xf, 1024, W16, 1024, 1024, nullptr, Qf, 1024, 1.f, bq, nullptr);

  // 3. rowsums of E,F (after Q proj so R0+4MiB is reusable)
  k_rowsum<<<128, 256, 0, stream>>>(E, F, rowsum);

  // 4. EX = [E;F]·X_b  (split-K=4) -> reduce to f16
  k_exfx<<<dim3(8, 4, 16), 256, 0, stream>>>(EF16, XT, part);
  k_reduce2<<<2048, 256, 0, stream>>>(part, EXf);

  // 5. Kp = EX·Wk^T, Vp^T = Wv·FX^T (split-K=2) -> reduce + rank-1 bias
  k_kpvp<<<dim3(8, 8, 4), 256, 0, stream>>>(EXf, W16, part2);
  k_reduce3<<<2048, 256, 0, stream>>>(part2, KpVp, rowsum, bk, bv);

  // 6. scores -> d_out attn region (fp32)
  k_scores<<<dim3(2, 32, 64), 256, 0, stream>>>(Qf, KpVp, S);

  // 7. per-batch: softmax -> P (R0), then out_pre = P·Vp (R1)
  for (int b = 0; b < 4; ++b) {
    k_softmax<<<16384, 256, 0, stream>>>(S + (size_t)b * 16 * 4096 * 256, Pf);
    k_pv<<<dim3(1, 32, 16), 128, 0, stream>>>(Pf, KpVp + (size_t)4 * 262144, OPf, b);
  }

  // 8. out = out_pre·Wo^T + bo
  k_gemm<2, 2, true><<<dim3(8, 128), 256, 0, stream>>>(
      OPf, 1024, W16 + 3 * 1048576, 1024, 1024, out, nullptr, 1024, 1.f, bo, nullptr);
}

// Round 2
// 724.403 us; speedup vs baseline: 1.0462x; 1.0462x over previous
//
#include <hip/hip_runtime.h>

typedef _Float16 f16;
typedef __attribute__((ext_vector_type(8))) _Float16 f16x8;
typedef __attribute__((ext_vector_type(4))) _Float16 f16x4;
typedef __attribute__((ext_vector_type(4))) float f32x4;

// ---- global_load_lds width-16 helper (m97 pattern) ----
typedef const __attribute__((address_space(1))) unsigned int* gas_ptr;
typedef __attribute__((address_space(3))) unsigned int* las_ptr;

__device__ __forceinline__ void gload16(const f16* g, f16* l) {
  __builtin_amdgcn_global_load_lds((gas_ptr)g, (las_ptr)l, 16, 0, 0);
}

// =====================================================================
// Generic MFMA GEMM core: C[m,n] = scale * sum_k A[m,k]*B[n,k] (+bias)
// =====================================================================
template<int WM, int WN, bool OUT32>
__device__ __forceinline__ void gemm_core(
    const f16* __restrict__ A, int lda,
    const f16* __restrict__ B, int ldb,
    int kLen,
    f16* lsA, f16* lsB,
    float* __restrict__ C32, f16* __restrict__ C16, int ldc,
    float scale, const float* __restrict__ biasC, const float* __restrict__ biasR)
{
  constexpr int T   = WM * WN * 64;      // threads per block
  constexpr int nA  = (WM * 64 * 8) / T; // global_load_lds insts for A tile
  constexpr int nB  = (WN * 64 * 8) / T;
  constexpr int RPI = T / 8;             // rows staged per inst
  const int t    = threadIdx.x;
  const int lane = t & 63;
  const int wave = t >> 6;
  const int wm   = wave / WN;
  const int wn   = wave % WN;

  f32x4 acc[4][4];
  const f32x4 z4 = {0.f, 0.f, 0.f, 0.f};
#pragma unroll
  for (int i = 0; i < 4; ++i)
#pragma unroll
    for (int j = 0; j < 4; ++j) acc[i][j] = z4;

  const int r_ = t >> 3;            // row within staging group
  const int c_ = (t & 7) * 8;       // k offset (f16 units)
  const int ldsOff = (wave << 9);   // wave * 64 lanes * 8 f16

  for (int kt = 0; kt < kLen; kt += 64) {
#pragma unroll
    for (int i = 0; i < nA; ++i) {
      const f16* g = A + (size_t)(i * RPI + r_) * lda + kt + c_;
      gload16(g, lsA + i * (T * 8) + ldsOff);
    }
#pragma unroll
    for (int i = 0; i < nB; ++i) {
      const f16* g = B + (size_t)(i * RPI + r_) * ldb + kt + c_;
      gload16(g, lsB + i * (T * 8) + ldsOff);
    }
    __syncthreads();   // compiler drains vmcnt(0) before s_barrier
#pragma unroll
    for (int ks = 0; ks < 2; ++ks) {
      f16x8 af[4], bf[4];
#pragma unroll
      for (int i = 0; i < 4; ++i)
        af[i] = *(const f16x8*)&lsA[(wm * 64 + i * 16 + (lane & 15)) * 64 + ks * 32 + (lane >> 4) * 8];
#pragma unroll
      for (int j = 0; j < 4; ++j)
        bf[j] = *(const f16x8*)&lsB[(wn * 64 + j * 16 + (lane & 15)) * 64 + ks * 32 + (lane >> 4) * 8];
#pragma unroll
      for (int i = 0; i < 4; ++i)
#pragma unroll
        for (int j = 0; j < 4; ++j)
          acc[i][j] = __builtin_amdgcn_mfma_f32_16x16x32_f16(af[i], bf[j], acc[i][j], 0, 0, 0);
    }
    __syncthreads();
  }

  // epilogue: C/D layout col=lane&15, row=(lane>>4)*4+reg (m89-verified)
  const int lc = lane & 15;
  const int lr = (lane >> 4) * 4;
#pragma unroll
  for (int j = 0; j < 4; ++j) {
    const int col = wn * 64 + j * 16 + lc;
    const float bC = biasC ? biasC[col] : 0.f;
#pragma unroll
    for (int i = 0; i < 4; ++i) {
      const int rbase = wm * 64 + i * 16 + lr;
#pragma unroll
      for (int r = 0; r < 4; ++r) {
        const int row = rbase + r;
        float v = acc[i][j][r] * scale + bC;
        if (biasR) v += biasR[row];
        if (OUT32) C32[(size_t)row * ldc + col] = v;
        else       C16[(size_t)row * ldc + col] = (f16)v;
      }
    }
  }
}

// ---- generic single-GEMM wrapper ----
template<int WM, int WN, bool OUT32>
__global__ __launch_bounds__(WM * WN * 64) void k_gemm(
    const f16* A, int lda, const f16* B, int ldb, int kLen,
    float* C32, f16* C16, int ldc, float scale,
    const float* biasC, const float* biasR)
{
  __shared__ f16 lsA[WM * 64 * 64];
  __shared__ f16 lsB[WN * 64 * 64];
  const size_t rt = blockIdx.y, ct = blockIdx.x;
  gemm_core<WM, WN, OUT32>(
      A + rt * (WM * 64) * (size_t)lda, lda,
      B + ct * (WN * 64) * (size_t)ldb, ldb, kLen,
      lsA, lsB,
      OUT32 ? C32 + rt * (WM * 64) * (size_t)ldc + ct * (WN * 64) : nullptr,
      OUT32 ? nullptr : C16 + rt * (WM * 64) * (size_t)ldc + ct * (WN * 64), ldc,
      scale,
      biasC ? biasC + ct * (WN * 64) : nullptr,
      biasR ? biasR + rt * (WM * 64) : nullptr);
}

// ---- cast x -> f16 in BOTH layouts: Xf (b*4096 x 1024) and XT (b, 1024, 4096) ----
__global__ __launch_bounds__(256) void k_cast_xt(const float* __restrict__ x,
                                                 f16* __restrict__ Xf,
                                                 f16* __restrict__ XT)
{
  __shared__ f16 tile[64][68];
  const int b = blockIdx.z, bi = blockIdx.y, bj = blockIdx.x;
  const int r0 = threadIdx.x >> 4;
  const int c4 = (threadIdx.x & 15) * 4;
  const float* xb = x + ((size_t)b * 4096 + (size_t)bi * 64) * 1024 + bj * 64;
#pragma unroll
  for (int rr = 0; rr < 4; ++rr) {
    const int row = rr * 16 + r0;
    const float4 v = *(const float4*)(xb + (size_t)row * 1024 + c4);
    f16x4 h = {(f16)v.x, (f16)v.y, (f16)v.z, (f16)v.w};
    *(f16x4*)&tile[row][c4] = h;
    *(f16x4*)(Xf + ((size_t)b * 4096 + (size_t)bi * 64 + row) * 1024 + bj * 64 + c4) = h;
  }
  __syncthreads();
#pragma unroll
  for (int rr = 0; rr < 4; ++rr) {
    const int col = rr * 16 + r0;
    f16x4 h = {tile[c4 + 0][col], tile[c4 + 1][col], tile[c4 + 2][col], tile[c4 + 3][col]};
    *(f16x4*)(XT + ((size_t)b * 1024 + (size_t)bj * 64 + col) * 4096 + (size_t)bi * 64 + c4) = h;
  }
}

// ---- cast weights -> f16: Wq,Wk,Wv,Wo then E,F ----
__global__ __launch_bounds__(256) void k_cast_w(
    const float* w0, const float* w1, const float* w2,
    const float* w3, const float* w4, const float* w5, f16* __restrict__ d)
{
  const size_t i = ((size_t)blockIdx.x * 256 + threadIdx.x) * 4;
  const int seg = (int)(i >> 20);
  const float* s = (seg == 0) ? w0 : (seg == 1) ? w1 : (seg == 2) ? w2
                 : (seg == 3) ? w3 : (seg == 4) ? w4 : w5;
  const float4 v = *(const float4*)(s + (i & 1048575));
  f16x4 o = {(f16)v.x, (f16)v.y, (f16)v.z, (f16)v.w};
  *(f16x4*)(d + i) = o;
}

// ---- row sums of E and F for the rank-1 bias terms ----
__global__ __launch_bounds__(256) void k_rowsum(const float* __restrict__ E,
                                                const float* __restrict__ F,
                                                float* __restrict__ rs)
{
  const int r = blockIdx.x * 4 + (threadIdx.x >> 6);
  const int lane = threadIdx.x & 63;
  const float* src = (r < 256) ? (E + (size_t)r * 4096) : (F + (size_t)(r - 256) * 4096);
  float s = 0.f;
#pragma unroll
  for (int i = 0; i < 16; ++i) {
    const float4 v = *(const float4*)(src + i * 256 + lane * 4);
    s += v.x + v.y + v.z + v.w;
  }
#pragma unroll
  for (int o = 32; o; o >>= 1) s += __shfl_xor(s, o);
  if (lane == 0) rs[r] = s;
}

// ---- EX/FX: C[(E|F) r, m] = sum_n EF[r,n] * XT[b,m,n]; split-K=4 ----
__global__ __launch_bounds__(256) void k_exfx(const f16* __restrict__ EF,
                                              const f16* __restrict__ XT,
                                              float* __restrict__ part)
{
  __shared__ f16 lsA[128 * 64];
  __shared__ f16 lsB[128 * 64];
  const int z = blockIdx.z; const int b = z & 3; const int s = z >> 2;
  const int rt = blockIdx.y, ct = blockIdx.x;
  const f16* A = EF + (size_t)rt * 128 * 4096 + s * 1024;
  const f16* B = XT + (size_t)b * 1024 * 4096 + (size_t)ct * 128 * 4096 + s * 1024;
  float* C = part + (size_t)z * (512 * 1024) + (size_t)rt * 128 * 1024 + ct * 128;
  gemm_core<2, 2, true>(A, 4096, B, 4096, 1024, lsA, lsB, C, nullptr, 1024, 1.f, nullptr, nullptr);
}

// ---- reduce EX/FX split-K partials -> f16 (b, 512, 1024) ----
__global__ __launch_bounds__(256) void k_reduce2(const float* __restrict__ part,
                                                 f16* __restrict__ EXf)
{
  const size_t i = ((size_t)blockIdx.x * 256 + threadIdx.x) * 4;
  const size_t b = i >> 19;
  const size_t idx = i & 524287;
  const float4 a = *(const float4*)(part + (0 * 4 + b) * 524288 + idx);
  const float4 c1 = *(const float4*)(part + (1 * 4 + b) * 524288 + idx);
  const float4 c2 = *(const float4*)(part + (2 * 4 + b) * 524288 + idx);
  const float4 c3 = *(const float4*)(part + (3 * 4 + b) * 524288 + idx);
  f16x4 o = {(f16)(a.x + c1.x + c2.x + c3.x), (f16)(a.y + c1.y + c2.y + c3.y),
             (f16)(a.z + c1.z + c2.z + c3.z), (f16)(a.w + c1.w + c2.w + c3.w)};
  *(f16x4*)(EXf + i) = o;
}

// ---- Kp = EX·Wk^T ; Vp^T = Wv·FX^T ; split-K=2 ----
__global__ __launch_bounds__(256) void k_kpvp(const f16* __restrict__ EXf,
                                              const f16* __restrict__ W16,
                                              float* __restrict__ p2)
{
  __shared__ f16 lsA[128 * 64];
  __shared__ f16 lsB[128 * 64];
  const int z = blockIdx.z; const int which = z & 1; const int s = z >> 1;
  const int rt = blockIdx.y, ct = blockIdx.x;
  const f16 *A, *B;
  if (which == 0) {  // Kp
    const int b = rt >> 1, r0 = (rt & 1) * 128;
    A = EXf + ((size_t)b * 512 + r0) * 1024 + s * 512;
    B = W16 + 1048576 + (size_t)ct * 128 * 1024 + s * 512;        // Wk
  } else {           // Vp^T
    const int b = ct >> 1, r0 = (ct & 1) * 128;
    A = W16 + 2 * 1048576 + (size_t)rt * 128 * 1024 + s * 512;    // Wv
    B = EXf + ((size_t)b * 512 + 256 + r0) * 1024 + s * 512;
  }
  float* C = p2 + (size_t)(s * 2 + which) * 1048576 + (size_t)rt * 128 * 1024 + ct * 128;
  gemm_core<2, 2, true>(A, 1024, B, 1024, 512, lsA, lsB, C, nullptr, 1024, 1.f, nullptr, nullptr);
}

// ---- reduce Kp/Vp partials + rank-1 bias -> f16 KpVp region ----
__global__ __launch_bounds__(256) void k_reduce3(const float* __restrict__ p2,
                                                 f16* __restrict__ KpVp,
                                                 const float* __restrict__ rs,
                                                 const float* __restrict__ bk,
                                                 const float* __restrict__ bv)
{
  const size_t i = ((size_t)blockIdx.x * 256 + threadIdx.x) * 4;
  const int half = (int)(i >> 20);
  const size_t j = i & 1048575;
  size_t pidx; float r1[4];
  if (half == 0) {           // Kp
    const int r  = (int)((j >> 10) & 255);
    const int hd = (int)(j & 1023);
    pidx = j;
    const float se = rs[r];
#pragma unroll
    for (int t = 0; t < 4; ++t) r1[t] = se * bk[hd + t];
  } else {                   // VpT
    const int b  = (int)(j >> 18);
    const int hd = (int)((j >> 8) & 1023);
    const int r  = (int)(j & 255);
    pidx = (size_t)hd * 1024 + (size_t)b * 256 + r;
    const float bb = bv[hd];
#pragma unroll
    for (int t = 0; t < 4; ++t) r1[t] = bb * rs[256 + r + t];
  }
  const float4 a = *(const float4*)(p2 + (size_t)(0 * 2 + half) * 1048576 + pidx);
  const float4 c = *(const float4*)(p2 + (size_t)(1 * 2 + half) * 1048576 + pidx);
  f16x4 o = {(f16)(a.x + c.x + r1[0]), (f16)(a.y + c.y + r1[1]),
             (f16)(a.z + c.z + r1[2]), (f16)(a.w + c.w + r1[3])};
  *(f16x4*)(KpVp + i) = o;
}

// ---- stage 3: scores = Q·Kp^T / 8 -> fp32 (d_out attn region) ----
__global__ __launch_bounds__(256) void k_scores(const f16* __restrict__ Q,
                                                const f16* __restrict__ Kp,
                                                float* __restrict__ S)
{
  __shared__ f16 lsA[128 * 64];
  __shared__ f16 lsB[128 * 64];
  const int bh = blockIdx.z; const int b = bh >> 4; const int h = bh & 15;
  const size_t rt = blockIdx.y, ct = blockIdx.x;
  const f16* A = Q + (size_t)b * 4096 * 1024 + h * 64 + rt * 128 * 1024;
  const f16* B = Kp + (size_t)b * 262144 + h * 64 + ct * 128 * 1024;
  float* C = S + (size_t)bh * 4096 * 256 + rt * 128 * 256 + ct * 128;
  gemm_core<2, 2, true>(A, 1024, B, 1024, 64, lsA, lsB, C, nullptr, 256, 0.125f, nullptr, nullptr);
}

// =====================================================================
// Fused softmax + PV: one block per (rt, h, b) = 128 rows x 1 head.
// Reads S tile (128x256 f32) from d_out, softmax (16 lanes/row, shfl),
// P -> XOR-swizzled LDS f16; Vp^T tile staged via global_load_lds with
// pre-swizzled SOURCE (rule #21: linear dest + inv-swz src + swz read).
// PV: O[128x64] = P[128x256]·VpT^T, 4 waves (wm=w>>1 rows, wn=w&1 cols).
// P never touches HBM (-268 MB vs separate softmax+PV kernels).
// =====================================================================
__global__ __launch_bounds__(256) void k_pvsm(const float* __restrict__ S,
                                              const f16* __restrict__ VpT,
                                              f16* __restrict__ OP)
{
  __shared__ f16 lsP[128 * 256];   // 64 KB, rows 512B, byte ^= (row&7)<<4
  __shared__ f16 lsV[64 * 256];    // 32 KB, same swizzle
  const int rt = blockIdx.x, h = blockIdx.y, b = blockIdx.z;
  const int t = threadIdx.x, lane = t & 63, w = t >> 6;

  // ---- stage Vp^T tile (64 rows hd-local x 256 r) ----
  const char* Vb = (const char*)(VpT + ((size_t)b * 1024 + h * 64) * 256);
  {
    const int vrow = lane >> 5;          // 0..1
    const int voff = (lane & 31) * 16;   // 0..496 bytes
#pragma unroll
    for (int i = 0; i < 8; ++i) {
      const int row = i * 8 + w * 2 + vrow;
      const int so = voff ^ ((row & 7) << 4);
      gload16((const f16*)(Vb + (size_t)row * 512 + so),
              (f16*)((char*)lsV + i * 4096 + w * 1024));
    }
  }

  // ---- softmax: 8 passes x 16 rows; 16 lanes per row ----
  const float* Sb = S + (((size_t)(b * 16 + h)) * 4096 + (size_t)rt * 128) * 256;
  const int rg = t >> 4;        // 0..15
  const int li = t & 15;        // 0..15
#pragma unroll
  for (int it = 0; it < 8; ++it) {
    const int row = it * 16 + rg;
    const float* sr = Sb + (size_t)row * 256 + li * 16;
    const float4 v0 = *(const float4*)(sr + 0);
    const float4 v1 = *(const float4*)(sr + 4);
    const float4 v2 = *(const float4*)(sr + 8);
    const float4 v3 = *(const float4*)(sr + 12);
    float m = fmaxf(fmaxf(fmaxf(v0.x, v0.y), fmaxf(v0.z, v0.w)),
                    fmaxf(fmaxf(v1.x, v1.y), fmaxf(v1.z, v1.w)));
    m = fmaxf(m, fmaxf(fmaxf(fmaxf(v2.x, v2.y), fmaxf(v2.z, v2.w)),
                       fmaxf(fmaxf(v3.x, v3.y), fmaxf(v3.z, v3.w))));
#pragma unroll
    for (int o = 8; o; o >>= 1) m = fmaxf(m, __shfl_xor(m, o));
    float ev[16];
    ev[0]  = __expf(v0.x - m); ev[1]  = __expf(v0.y - m);
    ev[2]  = __expf(v0.z - m); ev[3]  = __expf(v0.w - m);
    ev[4]  = __expf(v1.x - m); ev[5]  = __expf(v1.y - m);
    ev[6]  = __expf(v1.z - m); ev[7]  = __expf(v1.w - m);
    ev[8]  = __expf(v2.x - m); ev[9]  = __expf(v2.y - m);
    ev[10] = __expf(v2.z - m); ev[11] = __expf(v2.w - m);
    ev[12] = __expf(v3.x - m); ev[13] = __expf(v3.y - m);
    ev[14] = __expf(v3.z - m); ev[15] = __expf(v3.w - m);
    float s = 0.f;
#pragma unroll
    for (int k2 = 0; k2 < 16; ++k2) s += ev[k2];
#pragma unroll
    for (int o = 8; o; o >>= 1) s += __shfl_xor(s, o);
    const float inv = 1.f / s;
    f16x8 h0, h1;
#pragma unroll
    for (int k2 = 0; k2 < 8; ++k2) {
      h0[k2] = (f16)(ev[k2] * inv);
      h1[k2] = (f16)(ev[8 + k2] * inv);
    }
    char* base = (char*)lsP + (size_t)row * 512;
    const int swz = (row & 7) << 4;
    *(f16x8*)(base + ((li * 32) ^ swz))      = h0;
    *(f16x8*)(base + ((li * 32 + 16) ^ swz)) = h1;
  }
  __syncthreads();   // drains gload16 vmcnt + orders P writes

  // ---- PV MFMA: O[128x64], per wave 64 rows x 32 cols ----
  const int wm = w >> 1, wn = w & 1;
  f32x4 acc[4][2];
  const f32x4 z4 = {0.f, 0.f, 0.f, 0.f};
#pragma unroll
  for (int i = 0; i < 4; ++i) { acc[i][0] = z4; acc[i][1] = z4; }
#pragma unroll
  for (int ks = 0; ks < 8; ++ks) {
    const int koff = ks * 64 + (lane >> 4) * 16;   // bytes into 512B row
    f16x8 af[4], bf[2];
#pragma unroll
    for (int i = 0; i < 4; ++i) {
      const int m = wm * 64 + i * 16 + (lane & 15);
      af[i] = *(const f16x8*)((const char*)lsP + (size_t)m * 512 + (koff ^ ((m & 7) << 4)));
    }
#pragma unroll
    for (int j = 0; j < 2; ++j) {
      const int n = wn * 32 + j * 16 + (lane & 15);
      bf[j] = *(const f16x8*)((const char*)lsV + (size_t)n * 512 + (koff ^ ((n & 7) << 4)));
    }
#pragma unroll
    for (int i = 0; i < 4; ++i)
#pragma unroll
      for (int j = 0; j < 2; ++j)
        acc[i][j] = __builtin_amdgcn_mfma_f32_16x16x32_f16(af[i], bf[j], acc[i][j], 0, 0, 0);
  }

  // epilogue: O f16 -> OP[b][rt*128+row][h*64+col]
  f16* Ob = OP + ((size_t)b * 4096 + (size_t)rt * 128) * 1024 + h * 64;
  const int lc = lane & 15, lr = (lane >> 4) * 4;
#pragma unroll
  for (int j = 0; j < 2; ++j) {
    const int col = wn * 32 + j * 16 + lc;
#pragma unroll
    for (int i = 0; i < 4; ++i) {
      const int rbase = wm * 64 + i * 16 + lr;
#pragma unroll
      for (int r = 0; r < 4; ++r)
        Ob[(size_t)(rbase + r) * 1024 + col] = (f16)acc[i][j][r];
    }
  }
}

// =====================================================================
// Workspace layout (144 MiB, regions time-aliased):
//  R0 @0      (32MiB): Xf16 -> EXf (4MiB) + rowsum @+4MiB
//  R1 @32MiB  (32MiB): XT16 -> out_pre16 (OPf)
//  R2 @64MiB  (32MiB): Q16
//  R3 @96MiB  (32MiB): EX split-K partials -> KpVp partials
//  tail @128MiB (16MiB): W16 (8MiB) + EF16 (4MiB) + KpVp (4MiB)
// P is never materialized (fused softmax+PV).
// =====================================================================
extern "C" void kernel_launch(void* const* d_in, const int* in_sizes, int n_in,
                              void* d_out, int out_size, void* d_ws, size_t ws_size,
                              hipStream_t stream) {
  const float* x  = (const float*)d_in[0];
  const float* Wq = (const float*)d_in[1];
  const float* bq = (const float*)d_in[2];
  const float* Wk = (const float*)d_in[3];
  const float* bk = (const float*)d_in[4];
  const float* Wv = (const float*)d_in[5];
  const float* bv = (const float*)d_in[6];
  const float* E  = (const float*)d_in[7];
  const float* F  = (const float*)d_in[8];
  const float* Wo = (const float*)d_in[9];
  const float* bo = (const float*)d_in[10];

  float* out = (float*)d_out;           // 16,777,216 f32
  float* S   = out + 16777216;          // attn_score region, 67,108,864 f32

  char* w = (char*)d_ws;
  f16*   Xf     = (f16*)w;                              // R0
  f16*   EXf    = (f16*)w;                              // R0 (after Xf dead)
  float* rowsum = (float*)(w + 4 * 1048576);            // R0 + 4MiB
  f16*   XT     = (f16*)(w + 33554432);                 // R1
  f16*   OPf    = (f16*)(w + 33554432);                 // R1 (after XT dead)
  f16*   Qf     = (f16*)(w + (size_t)2 * 33554432);     // R2
  float* part   = (float*)(w + (size_t)3 * 33554432);   // R3 (EX partials)
  float* part2  = (float*)(w + (size_t)3 * 33554432);   // R3 (KpVp partials)
  f16*   W16    = (f16*)(w + (size_t)4 * 33554432);     // tail
  f16*   EF16   = W16 + (size_t)4 * 1048576;
  f16*   KpVp   = (f16*)(w + (size_t)4 * 33554432 + 12582912);

  // 1. casts: x -> Xf + XT (transposed), weights -> f16
  k_cast_xt<<<dim3(16, 64, 4), 256, 0, stream>>>(x, Xf, XT);
  k_cast_w<<<6144, 256, 0, stream>>>(Wq, Wk, Wv, Wo, E, F, W16);

  // 2. Q projection (Xf last use)
  k_gemm<2, 2, false><<<dim3(8, 128), 256, 0, stream>>>(
      Xf, 1024, W16, 1024, 1024, nullptr, Qf, 1024, 1.f, bq, nullptr);

  // 3. rowsums of E,F
  k_rowsum<<<128, 256, 0, stream>>>(E, F, rowsum);

  // 4. EX = [E;F]·X_b  (split-K=4) -> reduce to f16
  k_exfx<<<dim3(8, 4, 16), 256, 0, stream>>>(EF16, XT, part);
  k_reduce2<<<2048, 256, 0, stream>>>(part, EXf);

  // 5. Kp = EX·Wk^T, Vp^T = Wv·FX^T (split-K=2) -> reduce + rank-1 bias
  k_kpvp<<<dim3(8, 8, 4), 256, 0, stream>>>(EXf, W16, part2);
  k_reduce3<<<2048, 256, 0, stream>>>(part2, KpVp, rowsum, bk, bv);

  // 6. scores -> d_out attn region (fp32)
  k_scores<<<dim3(2, 32, 64), 256, 0, stream>>>(Qf, KpVp, S);

  // 7. fused softmax + PV for ALL batches (P never hits HBM)
  k_pvsm<<<dim3(32, 16, 4), 256, 0, stream>>>(S, KpVp + (size_t)4 * 262144, OPf);

  // 8. out = out_pre·Wo^T + bo
  k_gemm<2, 2, true><<<dim3(8, 128), 256, 0, stream>>>(
      OPf, 1024, W16 + 3 * 1048576, 1024, 1024, out, nullptr, 1024, 1.f, bo, nullptr);
}

// Round 3
// 654.199 us; speedup vs baseline: 1.1585x; 1.1073x over previous
//
#include <hip/hip_runtime.h>

typedef _Float16 f16;
typedef __attribute__((ext_vector_type(8))) _Float16 f16x8;
typedef __attribute__((ext_vector_type(4))) _Float16 f16x4;
typedef __attribute__((ext_vector_type(4))) float f32x4;

// ---- global_load_lds width-16 helper (m97 pattern) ----
typedef const __attribute__((address_space(1))) unsigned int* gas_ptr;
typedef __attribute__((address_space(3))) unsigned int* las_ptr;

__device__ __forceinline__ void gload16(const f16* g, f16* l) {
  __builtin_amdgcn_global_load_lds((gas_ptr)g, (las_ptr)l, 16, 0, 0);
}

// =====================================================================
// Generic MFMA GEMM core: C[m,n] = scale * sum_k A[m,k]*B[n,k] (+bias)
// =====================================================================
template<int WM, int WN, bool OUT32>
__device__ __forceinline__ void gemm_core(
    const f16* __restrict__ A, int lda,
    const f16* __restrict__ B, int ldb,
    int kLen,
    f16* lsA, f16* lsB,
    float* __restrict__ C32, f16* __restrict__ C16, int ldc,
    float scale, const float* __restrict__ biasC, const float* __restrict__ biasR)
{
  constexpr int T   = WM * WN * 64;      // threads per block
  constexpr int nA  = (WM * 64 * 8) / T; // global_load_lds insts for A tile
  constexpr int nB  = (WN * 64 * 8) / T;
  constexpr int RPI = T / 8;             // rows staged per inst
  const int t    = threadIdx.x;
  const int lane = t & 63;
  const int wave = t >> 6;
  const int wm   = wave / WN;
  const int wn   = wave % WN;

  f32x4 acc[4][4];
  const f32x4 z4 = {0.f, 0.f, 0.f, 0.f};
#pragma unroll
  for (int i = 0; i < 4; ++i)
#pragma unroll
    for (int j = 0; j < 4; ++j) acc[i][j] = z4;

  const int r_ = t >> 3;            // row within staging group
  const int c_ = (t & 7) * 8;       // k offset (f16 units)
  const int ldsOff = (wave << 9);   // wave * 64 lanes * 8 f16

  for (int kt = 0; kt < kLen; kt += 64) {
#pragma unroll
    for (int i = 0; i < nA; ++i) {
      const f16* g = A + (size_t)(i * RPI + r_) * lda + kt + c_;
      gload16(g, lsA + i * (T * 8) + ldsOff);
    }
#pragma unroll
    for (int i = 0; i < nB; ++i) {
      const f16* g = B + (size_t)(i * RPI + r_) * ldb + kt + c_;
      gload16(g, lsB + i * (T * 8) + ldsOff);
    }
    __syncthreads();   // compiler drains vmcnt(0) before s_barrier
#pragma unroll
    for (int ks = 0; ks < 2; ++ks) {
      f16x8 af[4], bf[4];
#pragma unroll
      for (int i = 0; i < 4; ++i)
        af[i] = *(const f16x8*)&lsA[(wm * 64 + i * 16 + (lane & 15)) * 64 + ks * 32 + (lane >> 4) * 8];
#pragma unroll
      for (int j = 0; j < 4; ++j)
        bf[j] = *(const f16x8*)&lsB[(wn * 64 + j * 16 + (lane & 15)) * 64 + ks * 32 + (lane >> 4) * 8];
#pragma unroll
      for (int i = 0; i < 4; ++i)
#pragma unroll
        for (int j = 0; j < 4; ++j)
          acc[i][j] = __builtin_amdgcn_mfma_f32_16x16x32_f16(af[i], bf[j], acc[i][j], 0, 0, 0);
    }
    __syncthreads();
  }

  // epilogue: C/D layout col=lane&15, row=(lane>>4)*4+reg (m89-verified)
  const int lc = lane & 15;
  const int lr = (lane >> 4) * 4;
#pragma unroll
  for (int j = 0; j < 4; ++j) {
    const int col = wn * 64 + j * 16 + lc;
    const float bC = biasC ? biasC[col] : 0.f;
#pragma unroll
    for (int i = 0; i < 4; ++i) {
      const int rbase = wm * 64 + i * 16 + lr;
#pragma unroll
      for (int r = 0; r < 4; ++r) {
        const int row = rbase + r;
        float v = acc[i][j][r] * scale + bC;
        if (biasR) v += biasR[row];
        if (OUT32) C32[(size_t)row * ldc + col] = v;
        else       C16[(size_t)row * ldc + col] = (f16)v;
      }
    }
  }
}

// ---- generic single-GEMM wrapper ----
template<int WM, int WN, bool OUT32>
__global__ __launch_bounds__(WM * WN * 64) void k_gemm(
    const f16* A, int lda, const f16* B, int ldb, int kLen,
    float* C32, f16* C16, int ldc, float scale,
    const float* biasC, const float* biasR)
{
  __shared__ f16 lsA[WM * 64 * 64];
  __shared__ f16 lsB[WN * 64 * 64];
  const size_t rt = blockIdx.y, ct = blockIdx.x;
  gemm_core<WM, WN, OUT32>(
      A + rt * (WM * 64) * (size_t)lda, lda,
      B + ct * (WN * 64) * (size_t)ldb, ldb, kLen,
      lsA, lsB,
      OUT32 ? C32 + rt * (WM * 64) * (size_t)ldc + ct * (WN * 64) : nullptr,
      OUT32 ? nullptr : C16 + rt * (WM * 64) * (size_t)ldc + ct * (WN * 64), ldc,
      scale,
      biasC ? biasC + ct * (WN * 64) : nullptr,
      biasR ? biasR + rt * (WM * 64) : nullptr);
}

// ---- cast x -> f16 in BOTH layouts: Xf (b*4096 x 1024) and XT (b, 1024, 4096) ----
__global__ __launch_bounds__(256) void k_cast_xt(const float* __restrict__ x,
                                                 f16* __restrict__ Xf,
                                                 f16* __restrict__ XT)
{
  __shared__ f16 tile[64][68];
  const int b = blockIdx.z, bi = blockIdx.y, bj = blockIdx.x;
  const int r0 = threadIdx.x >> 4;
  const int c4 = (threadIdx.x & 15) * 4;
  const float* xb = x + ((size_t)b * 4096 + (size_t)bi * 64) * 1024 + bj * 64;
#pragma unroll
  for (int rr = 0; rr < 4; ++rr) {
    const int row = rr * 16 + r0;
    const float4 v = *(const float4*)(xb + (size_t)row * 1024 + c4);
    f16x4 h = {(f16)v.x, (f16)v.y, (f16)v.z, (f16)v.w};
    *(f16x4*)&tile[row][c4] = h;
    *(f16x4*)(Xf + ((size_t)b * 4096 + (size_t)bi * 64 + row) * 1024 + bj * 64 + c4) = h;
  }
  __syncthreads();
#pragma unroll
  for (int rr = 0; rr < 4; ++rr) {
    const int col = rr * 16 + r0;
    f16x4 h = {tile[c4 + 0][col], tile[c4 + 1][col], tile[c4 + 2][col], tile[c4 + 3][col]};
    *(f16x4*)(XT + ((size_t)b * 1024 + (size_t)bj * 64 + col) * 4096 + (size_t)bi * 64 + c4) = h;
  }
}

// ---- cast weights -> f16: Wq,Wk,Wv,Wo then E,F ----
__global__ __launch_bounds__(256) void k_cast_w(
    const float* w0, const float* w1, const float* w2,
    const float* w3, const float* w4, const float* w5, f16* __restrict__ d)
{
  const size_t i = ((size_t)blockIdx.x * 256 + threadIdx.x) * 4;
  const int seg = (int)(i >> 20);
  const float* s = (seg == 0) ? w0 : (seg == 1) ? w1 : (seg == 2) ? w2
                 : (seg == 3) ? w3 : (seg == 4) ? w4 : w5;
  const float4 v = *(const float4*)(s + (i & 1048575));
  f16x4 o = {(f16)v.x, (f16)v.y, (f16)v.z, (f16)v.w};
  *(f16x4*)(d + i) = o;
}

// ---- row sums of E and F for the rank-1 bias terms ----
__global__ __launch_bounds__(256) void k_rowsum(const float* __restrict__ E,
                                                const float* __restrict__ F,
                                                float* __restrict__ rs)
{
  const int r = blockIdx.x * 4 + (threadIdx.x >> 6);
  const int lane = threadIdx.x & 63;
  const float* src = (r < 256) ? (E + (size_t)r * 4096) : (F + (size_t)(r - 256) * 4096);
  float s = 0.f;
#pragma unroll
  for (int i = 0; i < 16; ++i) {
    const float4 v = *(const float4*)(src + i * 256 + lane * 4);
    s += v.x + v.y + v.z + v.w;
  }
#pragma unroll
  for (int o = 32; o; o >>= 1) s += __shfl_xor(s, o);
  if (lane == 0) rs[r] = s;
}

// ---- EX/FX: C[(E|F) r, m] = sum_n EF[r,n] * XT[b,m,n]; split-K=4 ----
__global__ __launch_bounds__(256) void k_exfx(const f16* __restrict__ EF,
                                              const f16* __restrict__ XT,
                                              float* __restrict__ part)
{
  __shared__ f16 lsA[128 * 64];
  __shared__ f16 lsB[128 * 64];
  const int z = blockIdx.z; const int b = z & 3; const int s = z >> 2;
  const int rt = blockIdx.y, ct = blockIdx.x;
  const f16* A = EF + (size_t)rt * 128 * 4096 + s * 1024;
  const f16* B = XT + (size_t)b * 1024 * 4096 + (size_t)ct * 128 * 4096 + s * 1024;
  float* C = part + (size_t)z * (512 * 1024) + (size_t)rt * 128 * 1024 + ct * 128;
  gemm_core<2, 2, true>(A, 4096, B, 4096, 1024, lsA, lsB, C, nullptr, 1024, 1.f, nullptr, nullptr);
}

// ---- reduce EX/FX split-K partials -> f16 (b, 512, 1024) ----
__global__ __launch_bounds__(256) void k_reduce2(const float* __restrict__ part,
                                                 f16* __restrict__ EXf)
{
  const size_t i = ((size_t)blockIdx.x * 256 + threadIdx.x) * 4;
  const size_t b = i >> 19;
  const size_t idx = i & 524287;
  const float4 a = *(const float4*)(part + (0 * 4 + b) * 524288 + idx);
  const float4 c1 = *(const float4*)(part + (1 * 4 + b) * 524288 + idx);
  const float4 c2 = *(const float4*)(part + (2 * 4 + b) * 524288 + idx);
  const float4 c3 = *(const float4*)(part + (3 * 4 + b) * 524288 + idx);
  f16x4 o = {(f16)(a.x + c1.x + c2.x + c3.x), (f16)(a.y + c1.y + c2.y + c3.y),
             (f16)(a.z + c1.z + c2.z + c3.z), (f16)(a.w + c1.w + c2.w + c3.w)};
  *(f16x4*)(EXf + i) = o;
}

// ---- Kp = EX·Wk^T ; Vp^T = Wv·FX^T ; split-K=2 ----
__global__ __launch_bounds__(256) void k_kpvp(const f16* __restrict__ EXf,
                                              const f16* __restrict__ W16,
                                              float* __restrict__ p2)
{
  __shared__ f16 lsA[128 * 64];
  __shared__ f16 lsB[128 * 64];
  const int z = blockIdx.z; const int which = z & 1; const int s = z >> 1;
  const int rt = blockIdx.y, ct = blockIdx.x;
  const f16 *A, *B;
  if (which == 0) {  // Kp
    const int b = rt >> 1, r0 = (rt & 1) * 128;
    A = EXf + ((size_t)b * 512 + r0) * 1024 + s * 512;
    B = W16 + 1048576 + (size_t)ct * 128 * 1024 + s * 512;        // Wk
  } else {           // Vp^T
    const int b = ct >> 1, r0 = (ct & 1) * 128;
    A = W16 + 2 * 1048576 + (size_t)rt * 128 * 1024 + s * 512;    // Wv
    B = EXf + ((size_t)b * 512 + 256 + r0) * 1024 + s * 512;
  }
  float* C = p2 + (size_t)(s * 2 + which) * 1048576 + (size_t)rt * 128 * 1024 + ct * 128;
  gemm_core<2, 2, true>(A, 1024, B, 1024, 512, lsA, lsB, C, nullptr, 1024, 1.f, nullptr, nullptr);
}

// ---- reduce Kp/Vp partials + rank-1 bias -> f16 KpVp region ----
__global__ __launch_bounds__(256) void k_reduce3(const float* __restrict__ p2,
                                                 f16* __restrict__ KpVp,
                                                 const float* __restrict__ rs,
                                                 const float* __restrict__ bk,
                                                 const float* __restrict__ bv)
{
  const size_t i = ((size_t)blockIdx.x * 256 + threadIdx.x) * 4;
  const int half = (int)(i >> 20);
  const size_t j = i & 1048575;
  size_t pidx; float r1[4];
  if (half == 0) {           // Kp
    const int r  = (int)((j >> 10) & 255);
    const int hd = (int)(j & 1023);
    pidx = j;
    const float se = rs[r];
#pragma unroll
    for (int t = 0; t < 4; ++t) r1[t] = se * bk[hd + t];
  } else {                   // VpT
    const int b  = (int)(j >> 18);
    const int hd = (int)((j >> 8) & 1023);
    const int r  = (int)(j & 255);
    pidx = (size_t)hd * 1024 + (size_t)b * 256 + r;
    const float bb = bv[hd];
#pragma unroll
    for (int t = 0; t < 4; ++t) r1[t] = bb * rs[256 + r + t];
  }
  const float4 a = *(const float4*)(p2 + (size_t)(0 * 2 + half) * 1048576 + pidx);
  const float4 c = *(const float4*)(p2 + (size_t)(1 * 2 + half) * 1048576 + pidx);
  f16x4 o = {(f16)(a.x + c.x + r1[0]), (f16)(a.y + c.y + r1[1]),
             (f16)(a.z + c.z + r1[2]), (f16)(a.w + c.w + r1[3])};
  *(f16x4*)(KpVp + i) = o;
}

// =====================================================================
// Fully fused attention: scores (swapped QK^T) + S store + in-register
// softmax + PV.  One block per (rt, h, b): 128 seq rows x 1 head.
// Swapped MFMA (A=Kp, B=Q) => C fragment col = seq row n, so each lane
// holds 64 of the 256 r-values of its n: softmax = in-lane + 2 shfl_xor.
// S is written once to d_out and NEVER read back (-268 MB).
// P goes through XOR-swizzled LDS (aliasing dead Q/K tiles) into the
// verified PV structure.  Q/K staging source-pre-swizzled (T2).
// =====================================================================
__global__ __launch_bounds__(256) void k_attn(const f16* __restrict__ Q,
                                              const f16* __restrict__ Kp,
                                              const f16* __restrict__ VpT,
                                              float* __restrict__ S,
                                              f16* __restrict__ OP)
{
  __shared__ char smem[98304];           // 96 KB
  f16* lsK = (f16*)smem;                 // 32 KB: Kp 256x64, swizzled rows (128B)
  f16* lsQ = (f16*)(smem + 32768);       // 16 KB: Q 128x64, swizzled rows
  f16* lsV = (f16*)(smem + 65536);       // 32 KB: VpT 64x256, swizzled rows (512B)
  // lsP (64 KB, P 128x256, swizzled 512B rows) aliases smem[0..65536) after QK^T

  const int rt = blockIdx.x, h = blockIdx.y, b = blockIdx.z;
  const int t = threadIdx.x, lane = t & 63, w = t >> 6;
  const int g = lane >> 4;               // quarter-wave 0..3
  const int c = lane & 15;

  // ---- phase 1: stage K (8 insts), Q (4 insts), V (8/wave) ----
  const int r_ = t >> 3;                                  // 0..31
  const int cswz = ((t & 7) * 16) ^ ((r_ & 7) << 4);      // pre-swizzled src col
  const char* Kg = (const char*)(Kp + (size_t)b * 262144 + h * 64);
  const char* Qg = (const char*)(Q + ((size_t)b * 4096 + (size_t)rt * 128) * 1024 + h * 64);
#pragma unroll
  for (int i = 0; i < 8; ++i)
    gload16((const f16*)(Kg + (size_t)(i * 32 + r_) * 2048 + cswz),
            lsK + i * 2048 + (w << 9));
#pragma unroll
  for (int i = 0; i < 4; ++i)
    gload16((const f16*)(Qg + (size_t)(i * 32 + r_) * 2048 + cswz),
            lsQ + i * 2048 + (w << 9));
  {
    const char* Vb = (const char*)(VpT + ((size_t)b * 1024 + h * 64) * 256);
    const int vrow = lane >> 5;
    const int voff = (lane & 31) * 16;
#pragma unroll
    for (int i = 0; i < 8; ++i) {
      const int row = i * 8 + w * 2 + vrow;
      const int so = voff ^ ((row & 7) << 4);
      gload16((const f16*)(Vb + (size_t)row * 512 + so),
              (f16*)((char*)lsV + i * 4096 + w * 1024));
    }
  }
  __syncthreads();

  // ---- phase 2: swapped scores  C[r, n] ; acc[i][j]: r=i*16+g*4+reg, n=w*32+j*16+c
  const int swz = (lane & 7) << 4;       // all our LDS rows have row&7 == lane&7
  f32x4 acc[16][2];
  const f32x4 z4 = {0.f, 0.f, 0.f, 0.f};
#pragma unroll
  for (int i = 0; i < 16; ++i) { acc[i][0] = z4; acc[i][1] = z4; }
#pragma unroll
  for (int ks = 0; ks < 2; ++ks) {
    const int koff = ks * 64 + g * 16;
    f16x8 bf[2];
#pragma unroll
    for (int j = 0; j < 2; ++j) {
      const int row = w * 32 + j * 16 + c;
      bf[j] = *(const f16x8*)((const char*)lsQ + row * 128 + (koff ^ swz));
    }
#pragma unroll
    for (int i = 0; i < 16; ++i) {
      const f16x8 af = *(const f16x8*)((const char*)lsK + (i * 16 + c) * 128 + (koff ^ swz));
      acc[i][0] = __builtin_amdgcn_mfma_f32_16x16x32_f16(af, bf[0], acc[i][0], 0, 0, 0);
      acc[i][1] = __builtin_amdgcn_mfma_f32_16x16x32_f16(af, bf[1], acc[i][1], 0, 0, 0);
    }
  }

  // ---- phase 3: scale + store S (n-major: S[n][r]) ----
  float* Sb = S + (((size_t)(b * 16 + h)) * 4096 + (size_t)rt * 128 + w * 32) * 256;
#pragma unroll
  for (int j = 0; j < 2; ++j)
#pragma unroll
    for (int i = 0; i < 16; ++i) {
      acc[i][j] *= 0.125f;
      *(f32x4*)(Sb + (size_t)(j * 16 + c) * 256 + i * 16 + g * 4) = acc[i][j];
    }

  // ---- phase 4: in-register softmax (per lane: 2 rows, 64 vals each) ----
  float pinv[2];
#pragma unroll
  for (int j = 0; j < 2; ++j) {
    float m = acc[0][j][0];
#pragma unroll
    for (int i = 0; i < 16; ++i)
      m = fmaxf(m, fmaxf(fmaxf(acc[i][j][0], acc[i][j][1]),
                         fmaxf(acc[i][j][2], acc[i][j][3])));
    m = fmaxf(m, __shfl_xor(m, 16));
    m = fmaxf(m, __shfl_xor(m, 32));
    float s = 0.f;
#pragma unroll
    for (int i = 0; i < 16; ++i)
#pragma unroll
      for (int r2 = 0; r2 < 4; ++r2) {
        const float e = __expf(acc[i][j][r2] - m);
        acc[i][j][r2] = e;
        s += e;
      }
    s += __shfl_xor(s, 16);
    s += __shfl_xor(s, 32);
    pinv[j] = 1.f / s;
  }

  // ---- phase 5: P -> swizzled LDS (aliases lsK/lsQ; barrier first) ----
  __syncthreads();                       // all waves done reading lsQ/lsK
  char* lsP = (char*)smem;
#pragma unroll
  for (int j = 0; j < 2; ++j) {
    const int n = w * 32 + j * 16 + c;
    char* base = lsP + n * 512;
#pragma unroll
    for (int i = 0; i < 16; ++i) {
      f16x4 p = {(f16)(acc[i][j][0] * pinv[j]), (f16)(acc[i][j][1] * pinv[j]),
                 (f16)(acc[i][j][2] * pinv[j]), (f16)(acc[i][j][3] * pinv[j])};
      *(f16x4*)(base + ((i * 32 + g * 8) ^ swz)) = p;
    }
  }
  __syncthreads();

  // ---- phase 6: PV  O[n, hd] = sum_r P[n,r] V[hd,r] ----
  f32x4 o[2][4];
#pragma unroll
  for (int i2 = 0; i2 < 2; ++i2)
#pragma unroll
    for (int jh = 0; jh < 4; ++jh) o[i2][jh] = z4;
#pragma unroll
  for (int ks = 0; ks < 8; ++ks) {
    const int koff = ks * 64 + g * 16;
    f16x8 pa[2];
#pragma unroll
    for (int i2 = 0; i2 < 2; ++i2) {
      const int n = w * 32 + i2 * 16 + c;
      pa[i2] = *(const f16x8*)(lsP + n * 512 + (koff ^ swz));
    }
#pragma unroll
    for (int jh = 0; jh < 4; ++jh) {
      const f16x8 vb = *(const f16x8*)((const char*)lsV + (jh * 16 + c) * 512 + (koff ^ swz));
      o[0][jh] = __builtin_amdgcn_mfma_f32_16x16x32_f16(pa[0], vb, o[0][jh], 0, 0, 0);
      o[1][jh] = __builtin_amdgcn_mfma_f32_16x16x32_f16(pa[1], vb, o[1][jh], 0, 0, 0);
    }
  }

  // ---- epilogue: OP[b][n][h*64+hd] f16 ----
  f16* Ob = OP + ((size_t)b * 4096 + (size_t)rt * 128 + w * 32) * 1024 + h * 64;
#pragma unroll
  for (int jh = 0; jh < 4; ++jh) {
    const int col = jh * 16 + c;
#pragma unroll
    for (int i2 = 0; i2 < 2; ++i2) {
      const int rb = i2 * 16 + g * 4;
#pragma unroll
      for (int r2 = 0; r2 < 4; ++r2)
        Ob[(size_t)(rb + r2) * 1024 + col] = (f16)o[i2][jh][r2];
    }
  }
}

// =====================================================================
// Workspace layout (144 MiB, regions time-aliased):
//  R0 @0      (32MiB): Xf16 -> EXf (4MiB) + rowsum @+4MiB
//  R1 @32MiB  (32MiB): XT16 -> out_pre16 (OPf)
//  R2 @64MiB  (32MiB): Q16
//  R3 @96MiB  (32MiB): EX split-K partials -> KpVp partials
//  tail @128MiB (16MiB): W16 (8MiB) + EF16 (4MiB) + KpVp (4MiB)
// P and S-readback never touch HBM (fully fused attention tail).
// =====================================================================
extern "C" void kernel_launch(void* const* d_in, const int* in_sizes, int n_in,
                              void* d_out, int out_size, void* d_ws, size_t ws_size,
                              hipStream_t stream) {
  const float* x  = (const float*)d_in[0];
  const float* Wq = (const float*)d_in[1];
  const float* bq = (const float*)d_in[2];
  const float* Wk = (const float*)d_in[3];
  const float* bk = (const float*)d_in[4];
  const float* Wv = (const float*)d_in[5];
  const float* bv = (const float*)d_in[6];
  const float* E  = (const float*)d_in[7];
  const float* F  = (const float*)d_in[8];
  const float* Wo = (const float*)d_in[9];
  const float* bo = (const float*)d_in[10];

  float* out = (float*)d_out;           // 16,777,216 f32
  float* S   = out + 16777216;          // attn_score region, 67,108,864 f32

  char* w = (char*)d_ws;
  f16*   Xf     = (f16*)w;                              // R0
  f16*   EXf    = (f16*)w;                              // R0 (after Xf dead)
  float* rowsum = (float*)(w + 4 * 1048576);            // R0 + 4MiB
  f16*   XT     = (f16*)(w + 33554432);                 // R1
  f16*   OPf    = (f16*)(w + 33554432);                 // R1 (after XT dead)
  f16*   Qf     = (f16*)(w + (size_t)2 * 33554432);     // R2
  float* part   = (float*)(w + (size_t)3 * 33554432);   // R3 (EX partials)
  float* part2  = (float*)(w + (size_t)3 * 33554432);   // R3 (KpVp partials)
  f16*   W16    = (f16*)(w + (size_t)4 * 33554432);     // tail
  f16*   EF16   = W16 + (size_t)4 * 1048576;
  f16*   KpVp   = (f16*)(w + (size_t)4 * 33554432 + 12582912);

  // 1. casts: x -> Xf + XT (transposed), weights -> f16
  k_cast_xt<<<dim3(16, 64, 4), 256, 0, stream>>>(x, Xf, XT);
  k_cast_w<<<6144, 256, 0, stream>>>(Wq, Wk, Wv, Wo, E, F, W16);

  // 2. Q projection (Xf last use)
  k_gemm<2, 2, false><<<dim3(8, 128), 256, 0, stream>>>(
      Xf, 1024, W16, 1024, 1024, nullptr, Qf, 1024, 1.f, bq, nullptr);

  // 3. rowsums of E,F
  k_rowsum<<<128, 256, 0, stream>>>(E, F, rowsum);

  // 4. EX = [E;F]·X_b  (split-K=4) -> reduce to f16
  k_exfx<<<dim3(8, 4, 16), 256, 0, stream>>>(EF16, XT, part);
  k_reduce2<<<2048, 256, 0, stream>>>(part, EXf);

  // 5. Kp = EX·Wk^T, Vp^T = Wv·FX^T (split-K=2) -> reduce + rank-1 bias
  k_kpvp<<<dim3(8, 8, 4), 256, 0, stream>>>(EXf, W16, part2);
  k_reduce3<<<2048, 256, 0, stream>>>(part2, KpVp, rowsum, bk, bv);

  // 6+7. fused scores + softmax + PV (S written once, never read)
  k_attn<<<dim3(32, 16, 4), 256, 0, stream>>>(
      Qf, KpVp, KpVp + (size_t)4 * 262144, S, OPf);

  // 8. out = out_pre·Wo^T + bo
  k_gemm<2, 2, true><<<dim3(8, 128), 256, 0, stream>>>(
      OPf, 1024, W16 + 3 * 1048576, 1024, 1024, out, nullptr, 1024, 1.f, bo, nullptr);
}

// Round 4
// 599.466 us; speedup vs baseline: 1.2642x; 1.0913x over previous
//
#include <hip/hip_runtime.h>

typedef _Float16 f16;
typedef __attribute__((ext_vector_type(8))) _Float16 f16x8;
typedef __attribute__((ext_vector_type(4))) _Float16 f16x4;
typedef __attribute__((ext_vector_type(4))) float f32x4;

// ---- global_load_lds width-16 helper (m97 pattern) ----
typedef const __attribute__((address_space(1))) unsigned int* gas_ptr;
typedef __attribute__((address_space(3))) unsigned int* las_ptr;

__device__ __forceinline__ void gload16(const f16* g, f16* l) {
  __builtin_amdgcn_global_load_lds((gas_ptr)g, (las_ptr)l, 16, 0, 0);
}

// =====================================================================
// Generic MFMA GEMM core: C[m,n] = scale * sum_k A[m,k]*B[n,k] (+bias)
// (m97-style 1-phase structure; used for the small/medium GEMMs)
// =====================================================================
template<int WM, int WN, bool OUT32>
__device__ __forceinline__ void gemm_core(
    const f16* __restrict__ A, int lda,
    const f16* __restrict__ B, int ldb,
    int kLen,
    f16* lsA, f16* lsB,
    float* __restrict__ C32, f16* __restrict__ C16, int ldc,
    float scale, const float* __restrict__ biasC, const float* __restrict__ biasR)
{
  constexpr int T   = WM * WN * 64;      // threads per block
  constexpr int nA  = (WM * 64 * 8) / T; // global_load_lds insts for A tile
  constexpr int nB  = (WN * 64 * 8) / T;
  constexpr int RPI = T / 8;             // rows staged per inst
  const int t    = threadIdx.x;
  const int lane = t & 63;
  const int wave = t >> 6;
  const int wm   = wave / WN;
  const int wn   = wave % WN;

  f32x4 acc[4][4];
  const f32x4 z4 = {0.f, 0.f, 0.f, 0.f};
#pragma unroll
  for (int i = 0; i < 4; ++i)
#pragma unroll
    for (int j = 0; j < 4; ++j) acc[i][j] = z4;

  const int r_ = t >> 3;            // row within staging group
  const int c_ = (t & 7) * 8;       // k offset (f16 units)
  const int ldsOff = (wave << 9);   // wave * 64 lanes * 8 f16

  for (int kt = 0; kt < kLen; kt += 64) {
#pragma unroll
    for (int i = 0; i < nA; ++i) {
      const f16* g = A + (size_t)(i * RPI + r_) * lda + kt + c_;
      gload16(g, lsA + i * (T * 8) + ldsOff);
    }
#pragma unroll
    for (int i = 0; i < nB; ++i) {
      const f16* g = B + (size_t)(i * RPI + r_) * ldb + kt + c_;
      gload16(g, lsB + i * (T * 8) + ldsOff);
    }
    __syncthreads();   // compiler drains vmcnt(0) before s_barrier
#pragma unroll
    for (int ks = 0; ks < 2; ++ks) {
      f16x8 af[4], bf[4];
#pragma unroll
      for (int i = 0; i < 4; ++i)
        af[i] = *(const f16x8*)&lsA[(wm * 64 + i * 16 + (lane & 15)) * 64 + ks * 32 + (lane >> 4) * 8];
#pragma unroll
      for (int j = 0; j < 4; ++j)
        bf[j] = *(const f16x8*)&lsB[(wn * 64 + j * 16 + (lane & 15)) * 64 + ks * 32 + (lane >> 4) * 8];
#pragma unroll
      for (int i = 0; i < 4; ++i)
#pragma unroll
        for (int j = 0; j < 4; ++j)
          acc[i][j] = __builtin_amdgcn_mfma_f32_16x16x32_f16(af[i], bf[j], acc[i][j], 0, 0, 0);
    }
    __syncthreads();
  }

  // epilogue: C/D layout col=lane&15, row=(lane>>4)*4+reg (m89-verified)
  const int lc = lane & 15;
  const int lr = (lane >> 4) * 4;
#pragma unroll
  for (int j = 0; j < 4; ++j) {
    const int col = wn * 64 + j * 16 + lc;
    const float bC = biasC ? biasC[col] : 0.f;
#pragma unroll
    for (int i = 0; i < 4; ++i) {
      const int rbase = wm * 64 + i * 16 + lr;
#pragma unroll
      for (int r = 0; r < 4; ++r) {
        const int row = rbase + r;
        float v = acc[i][j][r] * scale + bC;
        if (biasR) v += biasR[row];
        if (OUT32) C32[(size_t)row * ldc + col] = v;
        else       C16[(size_t)row * ldc + col] = (f16)v;
      }
    }
  }
}

// =====================================================================
// 256x256 multi-phase GEMM (T2+T3+T4+T5 port): BK=32, quad-buffered LDS
// (128 KiB), 8 waves, 2 sub-phases per K-tile, counted vmcnt(4) (2-tile
// prefetch depth, never drained in steady state), raw s_barrier (NO
// __syncthreads — it would drain vmcnt), paired-row XOR LDS layout
// applied on BOTH the pre-swizzled global source and the ds_read addr.
// C[m,n] = sum_k A[m,k]B[n,k] + biasC[n].  M%256==0, N%256==0, K%32==0,
// K>=96. Grid: 1-D nblocks = (M/256)*(N/256) (multiple of 8), 512 thr.
// =====================================================================
template<bool OUT32>
__global__ __launch_bounds__(512) void k_gemm256(
    const f16* __restrict__ A, int lda,
    const f16* __restrict__ B, int ldb,
    int kLen, int nct,
    float* __restrict__ C32, f16* __restrict__ C16, int ldc,
    const float* __restrict__ biasC)
{
  __shared__ f16 ls[4][2][8192];   // [buf][A|B][16KB], 128 KiB total

  // bijective XCD swizzle (gridDim.x % 8 == 0)
  const int cpx = gridDim.x >> 3;
  const int wg  = (blockIdx.x & 7) * cpx + (blockIdx.x >> 3);
  const int rt  = wg / nct, ct = wg % nct;

  const int t    = threadIdx.x;
  const int lane = t & 63;
  const int w    = t >> 6;
  const int wm   = w >> 2;          // 0..1
  const int wn   = w & 3;           // 0..3
  const int c    = lane & 15;
  const int g    = lane >> 4;
  const int ch   = c >> 1;
  const int c1   = c & 1;
  const int jsw  = (g ^ (ch & 3)) << 4;   // swizzled 16B-chunk byte offset

  const f16* Ab = A + (size_t)rt * 256 * lda;
  const f16* Bb = B + (size_t)ct * 256 * ldb;

  // staging decode: thread t stages rows {srow, srow+128} chunk q=(t&3)^((t>>3)&3)
  const int srow = ((t >> 3) << 1) + ((t >> 2) & 1);
  const int sj   = ((t & 3) ^ ((t >> 3) & 3)) * 8;        // f16 units
  const int NT   = kLen >> 5;

#define STAGE_A(tile) { const int kt_ = (tile) * 32; f16* d_ = &ls[(tile) & 3][0][0]; \
    gload16(Ab + (size_t)srow * lda + kt_ + sj, d_ + t * 8); \
    gload16(Ab + (size_t)(srow + 128) * lda + kt_ + sj, d_ + 4096 + t * 8); }
#define STAGE_B(tile) { const int kt_ = (tile) * 32; f16* d_ = &ls[(tile) & 3][1][0]; \
    gload16(Bb + (size_t)srow * ldb + kt_ + sj, d_ + t * 8); \
    gload16(Bb + (size_t)(srow + 128) * ldb + kt_ + sj, d_ + 4096 + t * 8); }

  // prologue: stage tiles 0,1; guarantee tile 0 resident before any read
  STAGE_A(0); STAGE_B(0);
  STAGE_A(1); STAGE_B(1);
  asm volatile("s_waitcnt vmcnt(4)" ::: "memory");
  __builtin_amdgcn_s_barrier();

  f32x4 acc[8][4];
  const f32x4 z4 = {0.f, 0.f, 0.f, 0.f};
#pragma unroll
  for (int i = 0; i < 8; ++i)
#pragma unroll
    for (int j = 0; j < 4; ++j) acc[i][j] = z4;

  for (int tt = 0; tt < NT; ++tt) {
    const char* lA = (const char*)&ls[tt & 3][0][0];
    const char* lB = (const char*)&ls[tt & 3][1][0];
    f16x8 af[8], bf[4];
    // ---- sub-phase 1: read af[0..3] + bf[0..3], stage A-half of tile+2 ----
#pragma unroll
    for (int mf = 0; mf < 4; ++mf)
      af[mf] = *(const f16x8*)(lA + (size_t)(wm * 64 + mf * 8 + ch) * 128 + c1 * 64 + jsw);
#pragma unroll
    for (int nf = 0; nf < 4; ++nf)
      bf[nf] = *(const f16x8*)(lB + (size_t)(wn * 32 + nf * 8 + ch) * 128 + c1 * 64 + jsw);
    if (tt + 2 < NT) STAGE_A(tt + 2);
    __builtin_amdgcn_s_barrier();
    __builtin_amdgcn_s_setprio(1);
#pragma unroll
    for (int mf = 0; mf < 4; ++mf)
#pragma unroll
      for (int nf = 0; nf < 4; ++nf)
        acc[mf][nf] = __builtin_amdgcn_mfma_f32_16x16x32_f16(af[mf], bf[nf], acc[mf][nf], 0, 0, 0);
    __builtin_amdgcn_s_setprio(0);
    // ---- sub-phase 2: read af[4..7], stage B-half of tile+2, vmcnt once/tile ----
#pragma unroll
    for (int mf = 4; mf < 8; ++mf)
      af[mf] = *(const f16x8*)(lA + (size_t)(wm * 64 + mf * 8 + ch) * 128 + c1 * 64 + jsw);
    if (tt + 2 < NT) {
      STAGE_B(tt + 2);
      asm volatile("s_waitcnt vmcnt(4)" ::: "memory");   // tile tt+1 resident
    } else {
      asm volatile("s_waitcnt vmcnt(0)" ::: "memory");   // tail drain
    }
    __builtin_amdgcn_s_barrier();
    __builtin_amdgcn_s_setprio(1);
#pragma unroll
    for (int mf = 4; mf < 8; ++mf)
#pragma unroll
      for (int nf = 0; nf < 4; ++nf)
        acc[mf][nf] = __builtin_amdgcn_mfma_f32_16x16x32_f16(af[mf], bf[nf], acc[mf][nf], 0, 0, 0);
    __builtin_amdgcn_s_setprio(0);
  }
#undef STAGE_A
#undef STAGE_B

  // epilogue: m = rt*256 + wm*128 + mf*16 + g*4 + r ; n = ct*256 + wn*64 + nf*16 + c
#pragma unroll
  for (int nf = 0; nf < 4; ++nf) {
    const int col = ct * 256 + wn * 64 + nf * 16 + c;
    const float bC = biasC ? biasC[col] : 0.f;
#pragma unroll
    for (int mf = 0; mf < 8; ++mf) {
      const int rbase = rt * 256 + wm * 128 + mf * 16 + g * 4;
#pragma unroll
      for (int r = 0; r < 4; ++r) {
        const float v = acc[mf][nf][r] + bC;
        if (OUT32) __builtin_nontemporal_store(v, C32 + (size_t)(rbase + r) * ldc + col);
        else       C16[(size_t)(rbase + r) * ldc + col] = (f16)v;
      }
    }
  }
}

// ---- generic single-GEMM wrapper (kept for fallback/reference) ----
template<int WM, int WN, bool OUT32>
__global__ __launch_bounds__(WM * WN * 64) void k_gemm(
    const f16* A, int lda, const f16* B, int ldb, int kLen,
    float* C32, f16* C16, int ldc, float scale,
    const float* biasC, const float* biasR)
{
  __shared__ f16 lsA[WM * 64 * 64];
  __shared__ f16 lsB[WN * 64 * 64];
  const size_t rt = blockIdx.y, ct = blockIdx.x;
  gemm_core<WM, WN, OUT32>(
      A + rt * (WM * 64) * (size_t)lda, lda,
      B + ct * (WN * 64) * (size_t)ldb, ldb, kLen,
      lsA, lsB,
      OUT32 ? C32 + rt * (WM * 64) * (size_t)ldc + ct * (WN * 64) : nullptr,
      OUT32 ? nullptr : C16 + rt * (WM * 64) * (size_t)ldc + ct * (WN * 64), ldc,
      scale,
      biasC ? biasC + ct * (WN * 64) : nullptr,
      biasR ? biasR + rt * (WM * 64) : nullptr);
}

// ---- cast x -> f16 in BOTH layouts: Xf (b*4096 x 1024) and XT (b, 1024, 4096) ----
__global__ __launch_bounds__(256) void k_cast_xt(const float* __restrict__ x,
                                                 f16* __restrict__ Xf,
                                                 f16* __restrict__ XT)
{
  __shared__ f16 tile[64][68];
  const int b = blockIdx.z, bi = blockIdx.y, bj = blockIdx.x;
  const int r0 = threadIdx.x >> 4;
  const int c4 = (threadIdx.x & 15) * 4;
  const float* xb = x + ((size_t)b * 4096 + (size_t)bi * 64) * 1024 + bj * 64;
#pragma unroll
  for (int rr = 0; rr < 4; ++rr) {
    const int row = rr * 16 + r0;
    const float4 v = *(const float4*)(xb + (size_t)row * 1024 + c4);
    f16x4 h = {(f16)v.x, (f16)v.y, (f16)v.z, (f16)v.w};
    *(f16x4*)&tile[row][c4] = h;
    *(f16x4*)(Xf + ((size_t)b * 4096 + (size_t)bi * 64 + row) * 1024 + bj * 64 + c4) = h;
  }
  __syncthreads();
#pragma unroll
  for (int rr = 0; rr < 4; ++rr) {
    const int col = rr * 16 + r0;
    f16x4 h = {tile[c4 + 0][col], tile[c4 + 1][col], tile[c4 + 2][col], tile[c4 + 3][col]};
    *(f16x4*)(XT + ((size_t)b * 1024 + (size_t)bj * 64 + col) * 4096 + (size_t)bi * 64 + c4) = h;
  }
}

// ---- cast weights -> f16: Wq,Wk,Wv,Wo then E,F ----
__global__ __launch_bounds__(256) void k_cast_w(
    const float* w0, const float* w1, const float* w2,
    const float* w3, const float* w4, const float* w5, f16* __restrict__ d)
{
  const size_t i = ((size_t)blockIdx.x * 256 + threadIdx.x) * 4;
  const int seg = (int)(i >> 20);
  const float* s = (seg == 0) ? w0 : (seg == 1) ? w1 : (seg == 2) ? w2
                 : (seg == 3) ? w3 : (seg == 4) ? w4 : w5;
  const float4 v = *(const float4*)(s + (i & 1048575));
  f16x4 o = {(f16)v.x, (f16)v.y, (f16)v.z, (f16)v.w};
  *(f16x4*)(d + i) = o;
}

// ---- row sums of E and F for the rank-1 bias terms ----
__global__ __launch_bounds__(256) void k_rowsum(const float* __restrict__ E,
                                                const float* __restrict__ F,
                                                float* __restrict__ rs)
{
  const int r = blockIdx.x * 4 + (threadIdx.x >> 6);
  const int lane = threadIdx.x & 63;
  const float* src = (r < 256) ? (E + (size_t)r * 4096) : (F + (size_t)(r - 256) * 4096);
  float s = 0.f;
#pragma unroll
  for (int i = 0; i < 16; ++i) {
    const float4 v = *(const float4*)(src + i * 256 + lane * 4);
    s += v.x + v.y + v.z + v.w;
  }
#pragma unroll
  for (int o = 32; o; o >>= 1) s += __shfl_xor(s, o);
  if (lane == 0) rs[r] = s;
}

// ---- EX/FX: C[(E|F) r, m] = sum_n EF[r,n] * XT[b,m,n]; split-K=4 ----
__global__ __launch_bounds__(256) void k_exfx(const f16* __restrict__ EF,
                                              const f16* __restrict__ XT,
                                              float* __restrict__ part)
{
  __shared__ f16 lsA[128 * 64];
  __shared__ f16 lsB[128 * 64];
  const int z = blockIdx.z; const int b = z & 3; const int s = z >> 2;
  const int rt = blockIdx.y, ct = blockIdx.x;
  const f16* A = EF + (size_t)rt * 128 * 4096 + s * 1024;
  const f16* B = XT + (size_t)b * 1024 * 4096 + (size_t)ct * 128 * 4096 + s * 1024;
  float* C = part + (size_t)z * (512 * 1024) + (size_t)rt * 128 * 1024 + ct * 128;
  gemm_core<2, 2, true>(A, 4096, B, 4096, 1024, lsA, lsB, C, nullptr, 1024, 1.f, nullptr, nullptr);
}

// ---- reduce EX/FX split-K partials -> f16 (b, 512, 1024) ----
__global__ __launch_bounds__(256) void k_reduce2(const float* __restrict__ part,
                                                 f16* __restrict__ EXf)
{
  const size_t i = ((size_t)blockIdx.x * 256 + threadIdx.x) * 4;
  const size_t b = i >> 19;
  const size_t idx = i & 524287;
  const float4 a = *(const float4*)(part + (0 * 4 + b) * 524288 + idx);
  const float4 c1 = *(const float4*)(part + (1 * 4 + b) * 524288 + idx);
  const float4 c2 = *(const float4*)(part + (2 * 4 + b) * 524288 + idx);
  const float4 c3 = *(const float4*)(part + (3 * 4 + b) * 524288 + idx);
  f16x4 o = {(f16)(a.x + c1.x + c2.x + c3.x), (f16)(a.y + c1.y + c2.y + c3.y),
             (f16)(a.z + c1.z + c2.z + c3.z), (f16)(a.w + c1.w + c2.w + c3.w)};
  *(f16x4*)(EXf + i) = o;
}

// ---- Kp = EX·Wk^T ; Vp^T = Wv·FX^T ; split-K=2 ----
__global__ __launch_bounds__(256) void k_kpvp(const f16* __restrict__ EXf,
                                              const f16* __restrict__ W16,
                                              float* __restrict__ p2)
{
  __shared__ f16 lsA[128 * 64];
  __shared__ f16 lsB[128 * 64];
  const int z = blockIdx.z; const int which = z & 1; const int s = z >> 1;
  const int rt = blockIdx.y, ct = blockIdx.x;
  const f16 *A, *B;
  if (which == 0) {  // Kp
    const int b = rt >> 1, r0 = (rt & 1) * 128;
    A = EXf + ((size_t)b * 512 + r0) * 1024 + s * 512;
    B = W16 + 1048576 + (size_t)ct * 128 * 1024 + s * 512;        // Wk
  } else {           // Vp^T
    const int b = ct >> 1, r0 = (ct & 1) * 128;
    A = W16 + 2 * 1048576 + (size_t)rt * 128 * 1024 + s * 512;    // Wv
    B = EXf + ((size_t)b * 512 + 256 + r0) * 1024 + s * 512;
  }
  float* C = p2 + (size_t)(s * 2 + which) * 1048576 + (size_t)rt * 128 * 1024 + ct * 128;
  gemm_core<2, 2, true>(A, 1024, B, 1024, 512, lsA, lsB, C, nullptr, 1024, 1.f, nullptr, nullptr);
}

// ---- reduce Kp/Vp partials + rank-1 bias -> f16 KpVp region ----
__global__ __launch_bounds__(256) void k_reduce3(const float* __restrict__ p2,
                                                 f16* __restrict__ KpVp,
                                                 const float* __restrict__ rs,
                                                 const float* __restrict__ bk,
                                                 const float* __restrict__ bv)
{
  const size_t i = ((size_t)blockIdx.x * 256 + threadIdx.x) * 4;
  const int half = (int)(i >> 20);
  const size_t j = i & 1048575;
  size_t pidx; float r1[4];
  if (half == 0) {           // Kp
    const int r  = (int)((j >> 10) & 255);
    const int hd = (int)(j & 1023);
    pidx = j;
    const float se = rs[r];
#pragma unroll
    for (int t = 0; t < 4; ++t) r1[t] = se * bk[hd + t];
  } else {                   // VpT
    const int b  = (int)(j >> 18);
    const int hd = (int)((j >> 8) & 1023);
    const int r  = (int)(j & 255);
    pidx = (size_t)hd * 1024 + (size_t)b * 256 + r;
    const float bb = bv[hd];
#pragma unroll
    for (int t = 0; t < 4; ++t) r1[t] = bb * rs[256 + r + t];
  }
  const float4 a = *(const float4*)(p2 + (size_t)(0 * 2 + half) * 1048576 + pidx);
  const float4 c = *(const float4*)(p2 + (size_t)(1 * 2 + half) * 1048576 + pidx);
  f16x4 o = {(f16)(a.x + c.x + r1[0]), (f16)(a.y + c.y + r1[1]),
             (f16)(a.z + c.z + r1[2]), (f16)(a.w + c.w + r1[3])};
  *(f16x4*)(KpVp + i) = o;
}

// =====================================================================
// Fully fused attention: scores (swapped QK^T) + S store + in-register
// softmax + PV.  One block per (rt, h, b): 128 seq rows x 1 head.
// S stores are non-temporal (write-once, never read back).
// =====================================================================
__global__ __launch_bounds__(256) void k_attn(const f16* __restrict__ Q,
                                              const f16* __restrict__ Kp,
                                              const f16* __restrict__ VpT,
                                              float* __restrict__ S,
                                              f16* __restrict__ OP)
{
  __shared__ char smem[98304];           // 96 KB
  f16* lsK = (f16*)smem;                 // 32 KB: Kp 256x64, swizzled rows (128B)
  f16* lsQ = (f16*)(smem + 32768);       // 16 KB: Q 128x64, swizzled rows
  f16* lsV = (f16*)(smem + 65536);       // 32 KB: VpT 64x256, swizzled rows (512B)
  // lsP (64 KB, P 128x256, swizzled 512B rows) aliases smem[0..65536) after QK^T

  const int rt = blockIdx.x, h = blockIdx.y, b = blockIdx.z;
  const int t = threadIdx.x, lane = t & 63, w = t >> 6;
  const int g = lane >> 4;               // quarter-wave 0..3
  const int c = lane & 15;

  // ---- phase 1: stage K (8 insts), Q (4 insts), V (8/wave) ----
  const int r_ = t >> 3;                                  // 0..31
  const int cswz = ((t & 7) * 16) ^ ((r_ & 7) << 4);      // pre-swizzled src col
  const char* Kg = (const char*)(Kp + (size_t)b * 262144 + h * 64);
  const char* Qg = (const char*)(Q + ((size_t)b * 4096 + (size_t)rt * 128) * 1024 + h * 64);
#pragma unroll
  for (int i = 0; i < 8; ++i)
    gload16((const f16*)(Kg + (size_t)(i * 32 + r_) * 2048 + cswz),
            lsK + i * 2048 + (w << 9));
#pragma unroll
  for (int i = 0; i < 4; ++i)
    gload16((const f16*)(Qg + (size_t)(i * 32 + r_) * 2048 + cswz),
            lsQ + i * 2048 + (w << 9));
  {
    const char* Vb = (const char*)(VpT + ((size_t)b * 1024 + h * 64) * 256);
    const int vrow = lane >> 5;
    const int voff = (lane & 31) * 16;
#pragma unroll
    for (int i = 0; i < 8; ++i) {
      const int row = i * 8 + w * 2 + vrow;
      const int so = voff ^ ((row & 7) << 4);
      gload16((const f16*)(Vb + (size_t)row * 512 + so),
              (f16*)((char*)lsV + i * 4096 + w * 1024));
    }
  }
  __syncthreads();

  // ---- phase 2: swapped scores  C[r, n] ; acc[i][j]: r=i*16+g*4+reg, n=w*32+j*16+c
  const int swz = (lane & 7) << 4;       // all our LDS rows have row&7 == lane&7
  f32x4 acc[16][2];
  const f32x4 z4 = {0.f, 0.f, 0.f, 0.f};
#pragma unroll
  for (int i = 0; i < 16; ++i) { acc[i][0] = z4; acc[i][1] = z4; }
#pragma unroll
  for (int ks = 0; ks < 2; ++ks) {
    const int koff = ks * 64 + g * 16;
    f16x8 bf[2];
#pragma unroll
    for (int j = 0; j < 2; ++j) {
      const int row = w * 32 + j * 16 + c;
      bf[j] = *(const f16x8*)((const char*)lsQ + row * 128 + (koff ^ swz));
    }
#pragma unroll
    for (int i = 0; i < 16; ++i) {
      const f16x8 af = *(const f16x8*)((const char*)lsK + (i * 16 + c) * 128 + (koff ^ swz));
      acc[i][0] = __builtin_amdgcn_mfma_f32_16x16x32_f16(af, bf[0], acc[i][0], 0, 0, 0);
      acc[i][1] = __builtin_amdgcn_mfma_f32_16x16x32_f16(af, bf[1], acc[i][1], 0, 0, 0);
    }
  }

  // ---- phase 3: scale + store S (n-major: S[n][r]) non-temporal ----
  float* Sb = S + (((size_t)(b * 16 + h)) * 4096 + (size_t)rt * 128 + w * 32) * 256;
#pragma unroll
  for (int j = 0; j < 2; ++j)
#pragma unroll
    for (int i = 0; i < 16; ++i) {
      acc[i][j] *= 0.125f;
      __builtin_nontemporal_store(acc[i][j],
          (f32x4*)(Sb + (size_t)(j * 16 + c) * 256 + i * 16 + g * 4));
    }

  // ---- phase 4: in-register softmax (per lane: 2 rows, 64 vals each) ----
  float pinv[2];
#pragma unroll
  for (int j = 0; j < 2; ++j) {
    float m = acc[0][j][0];
#pragma unroll
    for (int i = 0; i < 16; ++i)
      m = fmaxf(m, fmaxf(fmaxf(acc[i][j][0], acc[i][j][1]),
                         fmaxf(acc[i][j][2], acc[i][j][3])));
    m = fmaxf(m, __shfl_xor(m, 16));
    m = fmaxf(m, __shfl_xor(m, 32));
    float s = 0.f;
#pragma unroll
    for (int i = 0; i < 16; ++i)
#pragma unroll
      for (int r2 = 0; r2 < 4; ++r2) {
        const float e = __expf(acc[i][j][r2] - m);
        acc[i][j][r2] = e;
        s += e;
      }
    s += __shfl_xor(s, 16);
    s += __shfl_xor(s, 32);
    pinv[j] = 1.f / s;
  }

  // ---- phase 5: P -> swizzled LDS (aliases lsK/lsQ; barrier first) ----
  __syncthreads();                       // all waves done reading lsQ/lsK
  char* lsP = (char*)smem;
#pragma unroll
  for (int j = 0; j < 2; ++j) {
    const int n = w * 32 + j * 16 + c;
    char* base = lsP + n * 512;
#pragma unroll
    for (int i = 0; i < 16; ++i) {
      f16x4 p = {(f16)(acc[i][j][0] * pinv[j]), (f16)(acc[i][j][1] * pinv[j]),
                 (f16)(acc[i][j][2] * pinv[j]), (f16)(acc[i][j][3] * pinv[j])};
      *(f16x4*)(base + ((i * 32 + g * 8) ^ swz)) = p;
    }
  }
  __syncthreads();

  // ---- phase 6: PV  O[n, hd] = sum_r P[n,r] V[hd,r] ----
  f32x4 o[2][4];
#pragma unroll
  for (int i2 = 0; i2 < 2; ++i2)
#pragma unroll
    for (int jh = 0; jh < 4; ++jh) o[i2][jh] = z4;
#pragma unroll
  for (int ks = 0; ks < 8; ++ks) {
    const int koff = ks * 64 + g * 16;
    f16x8 pa[2];
#pragma unroll
    for (int i2 = 0; i2 < 2; ++i2) {
      const int n = w * 32 + i2 * 16 + c;
      pa[i2] = *(const f16x8*)(lsP + n * 512 + (koff ^ swz));
    }
#pragma unroll
    for (int jh = 0; jh < 4; ++jh) {
      const f16x8 vb = *(const f16x8*)((const char*)lsV + (jh * 16 + c) * 512 + (koff ^ swz));
      o[0][jh] = __builtin_amdgcn_mfma_f32_16x16x32_f16(pa[0], vb, o[0][jh], 0, 0, 0);
      o[1][jh] = __builtin_amdgcn_mfma_f32_16x16x32_f16(pa[1], vb, o[1][jh], 0, 0, 0);
    }
  }

  // ---- epilogue: OP[b][n][h*64+hd] f16 ----
  f16* Ob = OP + ((size_t)b * 4096 + (size_t)rt * 128 + w * 32) * 1024 + h * 64;
#pragma unroll
  for (int jh = 0; jh < 4; ++jh) {
    const int col = jh * 16 + c;
#pragma unroll
    for (int i2 = 0; i2 < 2; ++i2) {
      const int rb = i2 * 16 + g * 4;
#pragma unroll
      for (int r2 = 0; r2 < 4; ++r2)
        Ob[(size_t)(rb + r2) * 1024 + col] = (f16)o[i2][jh][r2];
    }
  }
}

// =====================================================================
// Workspace layout (144 MiB, regions time-aliased):
//  R0 @0      (32MiB): Xf16 -> EXf (4MiB) + rowsum @+4MiB
//  R1 @32MiB  (32MiB): XT16 -> out_pre16 (OPf)
//  R2 @64MiB  (32MiB): Q16
//  R3 @96MiB  (32MiB): EX split-K partials -> KpVp partials
//  tail @128MiB (16MiB): W16 (8MiB) + EF16 (4MiB) + KpVp (4MiB)
// =====================================================================
extern "C" void kernel_launch(void* const* d_in, const int* in_sizes, int n_in,
                              void* d_out, int out_size, void* d_ws, size_t ws_size,
                              hipStream_t stream) {
  const float* x  = (const float*)d_in[0];
  const float* Wq = (const float*)d_in[1];
  const float* bq = (const float*)d_in[2];
  const float* Wk = (const float*)d_in[3];
  const float* bk = (const float*)d_in[4];
  const float* Wv = (const float*)d_in[5];
  const float* bv = (const float*)d_in[6];
  const float* E  = (const float*)d_in[7];
  const float* F  = (const float*)d_in[8];
  const float* Wo = (const float*)d_in[9];
  const float* bo = (const float*)d_in[10];

  float* out = (float*)d_out;           // 16,777,216 f32
  float* S   = out + 16777216;          // attn_score region, 67,108,864 f32

  char* w = (char*)d_ws;
  f16*   Xf     = (f16*)w;                              // R0
  f16*   EXf    = (f16*)w;                              // R0 (after Xf dead)
  float* rowsum = (float*)(w + 4 * 1048576);            // R0 + 4MiB
  f16*   XT     = (f16*)(w + 33554432);                 // R1
  f16*   OPf    = (f16*)(w + 33554432);                 // R1 (after XT dead)
  f16*   Qf     = (f16*)(w + (size_t)2 * 33554432);     // R2
  float* part   = (float*)(w + (size_t)3 * 33554432);   // R3 (EX partials)
  float* part2  = (float*)(w + (size_t)3 * 33554432);   // R3 (KpVp partials)
  f16*   W16    = (f16*)(w + (size_t)4 * 33554432);     // tail
  f16*   EF16   = W16 + (size_t)4 * 1048576;
  f16*   KpVp   = (f16*)(w + (size_t)4 * 33554432 + 12582912);

  // 1. casts: x -> Xf + XT (transposed), weights -> f16
  k_cast_xt<<<dim3(16, 64, 4), 256, 0, stream>>>(x, Xf, XT);
  k_cast_w<<<6144, 256, 0, stream>>>(Wq, Wk, Wv, Wo, E, F, W16);

  // 2. Q projection: 256x256 multi-phase GEMM (grid 64x4 = 256 = 1/CU)
  k_gemm256<false><<<256, 512, 0, stream>>>(
      Xf, 1024, W16, 1024, 1024, 4, nullptr, Qf, 1024, bq);

  // 3. rowsums of E,F
  k_rowsum<<<128, 256, 0, stream>>>(E, F, rowsum);

  // 4. EX = [E;F]·X_b  (split-K=4) -> reduce to f16
  k_exfx<<<dim3(8, 4, 16), 256, 0, stream>>>(EF16, XT, part);
  k_reduce2<<<2048, 256, 0, stream>>>(part, EXf);

  // 5. Kp = EX·Wk^T, Vp^T = Wv·FX^T (split-K=2) -> reduce + rank-1 bias
  k_kpvp<<<dim3(8, 8, 4), 256, 0, stream>>>(EXf, W16, part2);
  k_reduce3<<<2048, 256, 0, stream>>>(part2, KpVp, rowsum, bk, bv);

  // 6+7. fused scores + softmax + PV (S written once, never read)
  k_attn<<<dim3(32, 16, 4), 256, 0, stream>>>(
      Qf, KpVp, KpVp + (size_t)4 * 262144, S, OPf);

  // 8. out = out_pre·Wo^T + bo : 256x256 multi-phase GEMM, fp32 nt stores
  k_gemm256<true><<<256, 512, 0, stream>>>(
      OPf, 1024, W16 + 3 * 1048576, 1024, 1024, 4, out, nullptr, 1024, bo);
}